// Round 1
// baseline (7097.068 us; speedup 1.0000x reference)
//
#include <hip/hip_runtime.h>
#include <cmath>

#define NB 512
#define SEQ 301
#define ATT_SCALE 0.25f

// ---------------- K1: SSE gate: sq = sigmoid(dot(x[b,:,h,w,:], sse_w)+b); xs = x*sq
__global__ __launch_bounds__(64) void k_sse(const float* __restrict__ xin,
    const float* __restrict__ sw, const float* __restrict__ sb, float* __restrict__ xs) {
  int blk = blockIdx.x; int b = blk / 25, p = blk % 25; int lane = threadIdx.x;
  const float* src = xin + (size_t)b*7500 + p*300;
  float s = 0.f;
  for (int c = lane; c < 300; c += 64) s += src[c]*sw[c];
  #pragma unroll
  for (int o = 32; o > 0; o >>= 1) s += __shfl_down(s, o, 64);
  s = __shfl(s, 0, 64);
  float sq = 1.f/(1.f + __expf(-(s + sb[0])));
  float* dst = xs + (size_t)b*7500 + p*300;
  for (int c = lane; c < 300; c += 64) dst[c] = src[c]*sq;
}

// ---------------- K2: conv1 (16,1,3,3,7) VALID on (B,1,5,5,300) -> (B,16,3,3,294) + relu
__global__ __launch_bounds__(256) void k_conv1(const float* __restrict__ xs,
    const float* __restrict__ w, const float* __restrict__ bias, float* __restrict__ c1) {
  int blk = blockIdx.x; int b = blk/9; int dh = blk%9; int d0 = dh/3, h0 = dh%3;
  __shared__ float in_s[2700];   // 9 rows (kd,kh) x 300
  __shared__ float w_s[1008];    // 16 x 63
  int tid = threadIdx.x;
  for (int i = tid; i < 2700; i += 256) {
    int r = i/300, cc = i%300;
    int kd = r/3, kh = r%3;
    in_s[i] = xs[(size_t)b*7500 + (size_t)((d0+kd)*5 + (h0+kh))*300 + cc];
  }
  for (int i = tid; i < 1008; i += 256) w_s[i] = w[i];
  __syncthreads();
  for (int i = tid; i < 16*294; i += 256) {
    int o = i/294, wo = i%294;
    float acc = bias[o];
    const float* wp = &w_s[o*63];
    #pragma unroll
    for (int r = 0; r < 9; ++r) {
      const float* ip = &in_s[r*300 + wo];
      #pragma unroll
      for (int kw = 0; kw < 7; ++kw) acc += ip[kw]*wp[r*7 + kw];
    }
    c1[(((size_t)b*16 + o)*9 + dh)*294 + wo] = fmaxf(acc, 0.f);
  }
}

// ---------------- K3: conv2 (32,16,3,3,3) VALID on (B,16,3,3,294) -> (B,32,292) + relu
__global__ __launch_bounds__(256) void k_conv2(const float* __restrict__ c1,
    const float* __restrict__ w, const float* __restrict__ bias, float* __restrict__ c2) {
  int blk = blockIdx.x; int b = blk/4; int chunk = blk%4; int w0 = chunk*73;
  __shared__ float p_s[10800];   // [ci(16)][r(9)][w(75)]
  int tid = threadIdx.x;
  for (int i = tid; i < 10800; i += 256) {
    int ci = i/675; int rem = i%675; int r = rem/75; int ww = rem%75;
    p_s[i] = c1[(((size_t)b*16 + ci)*9 + r)*294 + w0 + ww];
  }
  __syncthreads();
  for (int i = tid; i < 32*73; i += 256) {
    int o = i/73, w2 = i%73;
    float acc = bias[o];
    const float* wp = &w[(size_t)o*432];
    #pragma unroll
    for (int ci = 0; ci < 16; ++ci) {
      #pragma unroll
      for (int r = 0; r < 9; ++r) {
        const float* ip = &p_s[(ci*9 + r)*75 + w2];
        #pragma unroll
        for (int kw = 0; kw < 3; ++kw) acc += ip[kw]*wp[ci*27 + r*3 + kw];
      }
    }
    c2[((size_t)b*32 + o)*292 + w0 + w2] = fmaxf(acc, 0.f);
  }
}

// ---------------- K4: dense1: y[b,o] = c2[b,:9344] . w[o,:] + b
__global__ __launch_bounds__(256) void k_dense1(const float* __restrict__ c2,
    const float* __restrict__ w, const float* __restrict__ bias, float* __restrict__ y) {
  int b = blockIdx.x; int tid = threadIdx.x; int lane = tid & 63; int wv = tid >> 6;
  const float* xrow = c2 + (size_t)b*9344;
  float acc[16];
  #pragma unroll
  for (int o = 0; o < 16; ++o) acc[o] = 0.f;
  int obase = wv*16;
  for (int k = lane; k < 9344; k += 64) {
    float xv = xrow[k];
    #pragma unroll
    for (int o = 0; o < 16; ++o) acc[o] += xv * w[(size_t)(obase+o)*9344 + k];
  }
  #pragma unroll
  for (int o = 0; o < 16; ++o) {
    float s = acc[o];
    #pragma unroll
    for (int off = 32; off; off >>= 1) s += __shfl_down(s, off, 64);
    if (lane == 0) y[(size_t)b*64 + obase + o] = s + bias[obase+o];
  }
}

// ---------------- K5: patch embed + cls + pos
__global__ __launch_bounds__(64) void k_patch(const float* __restrict__ xs,
    const float* __restrict__ pw, const float* __restrict__ pb,
    const float* __restrict__ cls, const float* __restrict__ pos, float* __restrict__ x) {
  int blk = blockIdx.x; int b = blk/SEQ; int s = blk%SEQ; int d = threadIdx.x;
  float acc;
  if (s == 0) {
    acc = cls[d] + pos[d];
  } else {
    acc = pb[d] + pos[s*64 + d];
    const float* patch = xs + (size_t)b*7500 + (size_t)(s-1)*25;
    const float* wr = pw + d*25;
    #pragma unroll
    for (int p = 0; p < 25; ++p) acc += patch[p]*wr[p];
  }
  x[(size_t)blk*64 + d] = acc;
}

// ---------------- K6: layernorm over dim 64 (one wave per row)
__global__ __launch_bounds__(64) void k_ln(const float* __restrict__ x,
    const float* __restrict__ g, const float* __restrict__ bt, float* __restrict__ xn) {
  int row = blockIdx.x; int d = threadIdx.x;
  float v = x[(size_t)row*64 + d];
  float m = v;
  #pragma unroll
  for (int o = 32; o; o >>= 1) m += __shfl_down(m, o, 64);
  m = __shfl(m, 0, 64) * (1.f/64.f);
  float c = v - m;
  float s2 = c*c;
  #pragma unroll
  for (int o = 32; o; o >>= 1) s2 += __shfl_down(s2, o, 64);
  s2 = __shfl(s2, 0, 64) * (1.f/64.f);
  xn[(size_t)row*64 + d] = c * rsqrtf(s2 + 1e-5f) * g[d] + bt[d];
}

// ---------------- K7: fused per-(b,h) attention: local QKV proj + online softmax
__global__ __launch_bounds__(256) void k_attn(const float* __restrict__ xn,
    const float* __restrict__ qkvw, float* __restrict__ ao) {
  int blk = blockIdx.x; int b = blk >> 2; int h = blk & 3;
  __shared__ alignas(16) float w_s[3072];      // q(16x64) k(16x64) v(16x64)
  __shared__ alignas(16) float K_s[SEQ*16];
  __shared__ alignas(16) float V_s[SEQ*16];
  int tid = threadIdx.x;
  for (int i = tid; i < 1024; i += 256) {
    w_s[i]        = qkvw[(size_t)(h*16)*64 + i];
    w_s[1024 + i] = qkvw[(size_t)(64 + h*16)*64 + i];
    w_s[2048 + i] = qkvw[(size_t)(128 + h*16)*64 + i];
  }
  __syncthreads();
  const float* xb = xn + (size_t)b*SEQ*64;
  for (int i = tid; i < SEQ*16; i += 256) {
    int s = i >> 4, d = i & 15;
    const float* xr = xb + (size_t)s*64;
    const float* wk = &w_s[1024 + d*64];
    const float* wv = &w_s[2048 + d*64];
    float ak = 0.f, av = 0.f;
    #pragma unroll 8
    for (int j = 0; j < 64; ++j) { float xv = xr[j]; ak += xv*wk[j]; av += xv*wv[j]; }
    K_s[i] = ak; V_s[i] = av;
  }
  __syncthreads();
  int s0 = tid*2;
  if (s0 >= SEQ) return;
  bool two = (s0 + 1 < SEQ);
  const float* xr0 = xb + (size_t)s0*64;
  const float* xr1 = xb + (size_t)(two ? s0+1 : s0)*64;
  float q0[16], q1[16];
  #pragma unroll
  for (int d = 0; d < 16; ++d) {
    const float* wq = &w_s[d*64];
    float a0 = 0.f, a1 = 0.f;
    #pragma unroll 8
    for (int j = 0; j < 64; ++j) { float wj = wq[j]; a0 += xr0[j]*wj; a1 += xr1[j]*wj; }
    q0[d] = a0*ATT_SCALE; q1[d] = a1*ATT_SCALE;
  }
  float m0 = -3.0e38f, m1 = -3.0e38f, l0 = 0.f, l1 = 0.f;
  float o0[16], o1[16];
  #pragma unroll
  for (int t = 0; t < 16; ++t) { o0[t] = 0.f; o1[t] = 0.f; }
  for (int j = 0; j < SEQ; ++j) {
    float kr[16], vr[16];
    const float4* kp = (const float4*)&K_s[j*16];
    const float4* vp = (const float4*)&V_s[j*16];
    *(float4*)&kr[0]  = kp[0]; *(float4*)&kr[4]  = kp[1];
    *(float4*)&kr[8]  = kp[2]; *(float4*)&kr[12] = kp[3];
    *(float4*)&vr[0]  = vp[0]; *(float4*)&vr[4]  = vp[1];
    *(float4*)&vr[8]  = vp[2]; *(float4*)&vr[12] = vp[3];
    float d0 = 0.f, d1 = 0.f;
    #pragma unroll
    for (int t = 0; t < 16; ++t) { d0 += q0[t]*kr[t]; d1 += q1[t]*kr[t]; }
    if (d0 > m0) {
      float f = __expf(m0 - d0); l0 *= f;
      #pragma unroll
      for (int t = 0; t < 16; ++t) o0[t] *= f;
      m0 = d0;
    }
    float p0 = __expf(d0 - m0); l0 += p0;
    #pragma unroll
    for (int t = 0; t < 16; ++t) o0[t] += p0*vr[t];
    if (d1 > m1) {
      float f = __expf(m1 - d1); l1 *= f;
      #pragma unroll
      for (int t = 0; t < 16; ++t) o1[t] *= f;
      m1 = d1;
    }
    float p1 = __expf(d1 - m1); l1 += p1;
    #pragma unroll
    for (int t = 0; t < 16; ++t) o1[t] += p1*vr[t];
  }
  float inv0 = 1.f/l0;
  float* dst0 = ao + ((size_t)b*SEQ + s0)*64 + h*16;
  #pragma unroll
  for (int t = 0; t < 16; ++t) dst0[t] = o0[t]*inv0;
  if (two) {
    float inv1 = 1.f/l1;
    float* dst1 = dst0 + 64;
    #pragma unroll
    for (int t = 0; t < 16; ++t) dst1[t] = o1[t]*inv1;
  }
}

// ---------------- K8: attn out proj + residual
__global__ __launch_bounds__(64) void k_attnout(const float* __restrict__ ao,
    const float* __restrict__ w, const float* __restrict__ bias, float* __restrict__ x) {
  int row = blockIdx.x; int d = threadIdx.x;
  __shared__ float o_s[64];
  o_s[d] = ao[(size_t)row*64 + d];
  __syncthreads();
  float acc = bias[d];
  const float* wr = w + d*64;
  #pragma unroll 8
  for (int j = 0; j < 64; ++j) acc += o_s[j]*wr[j];
  x[(size_t)row*64 + d] += acc;
}

// ---------------- K9: fused ln2 + ff1 + gelu + ff2 + residual
__global__ __launch_bounds__(64) void k_ff(float* __restrict__ x,
    const float* __restrict__ g, const float* __restrict__ bt,
    const float* __restrict__ w1, const float* __restrict__ b1,
    const float* __restrict__ w2, const float* __restrict__ b2) {
  int row = blockIdx.x; int d = threadIdx.x;
  float v = x[(size_t)row*64 + d];
  float m = v;
  #pragma unroll
  for (int o = 32; o; o >>= 1) m += __shfl_down(m, o, 64);
  m = __shfl(m, 0, 64) * (1.f/64.f);
  float c = v - m;
  float s2 = c*c;
  #pragma unroll
  for (int o = 32; o; o >>= 1) s2 += __shfl_down(s2, o, 64);
  s2 = __shfl(s2, 0, 64) * (1.f/64.f);
  float xnv = c * rsqrtf(s2 + 1e-5f) * g[d] + bt[d];
  __shared__ float xn_s[64];
  __shared__ float hid_s[8];
  xn_s[d] = xnv;
  __syncthreads();
  if (d < 8) {
    float a = b1[d];
    const float* wr = w1 + d*64;
    #pragma unroll 8
    for (int j = 0; j < 64; ++j) a += xn_s[j]*wr[j];
    hid_s[d] = 0.5f*a*(1.f + erff(a*0.70710678f));  // exact gelu
  }
  __syncthreads();
  float acc = b2[d];
  const float* w2r = w2 + d*8;
  #pragma unroll
  for (int t = 0; t < 8; ++t) acc += hid_s[t]*w2r[t];
  x[(size_t)row*64 + d] = v + acc;
}

// ---------------- K10: head: LN(concat(cls, y)) @ head_w.T + b
__global__ __launch_bounds__(128) void k_head(const float* __restrict__ x,
    const float* __restrict__ y, const float* __restrict__ g, const float* __restrict__ bt,
    const float* __restrict__ hw, const float* __restrict__ hb, float* __restrict__ out) {
  int b = blockIdx.x; int t = threadIdx.x; int lane = t & 63; int wv = t >> 6;
  float v = (t < 64) ? x[(size_t)b*SEQ*64 + t] : y[(size_t)b*64 + t - 64];
  __shared__ float rbuf[2];
  __shared__ float z_s[128];
  float s = v;
  #pragma unroll
  for (int o = 32; o; o >>= 1) s += __shfl_down(s, o, 64);
  if (lane == 0) rbuf[wv] = s;
  __syncthreads();
  float m = (rbuf[0] + rbuf[1]) * (1.f/128.f);
  __syncthreads();
  float c = v - m;
  float s2 = c*c;
  #pragma unroll
  for (int o = 32; o; o >>= 1) s2 += __shfl_down(s2, o, 64);
  if (lane == 0) rbuf[wv] = s2;
  __syncthreads();
  float var = (rbuf[0] + rbuf[1]) * (1.f/128.f);
  z_s[t] = c * rsqrtf(var + 1e-5f) * g[t] + bt[t];
  __syncthreads();
  if (t < 16) {
    float a = hb[t];
    const float* wr = hw + t*128;
    #pragma unroll 8
    for (int j = 0; j < 128; ++j) a += z_s[j]*wr[j];
    out[(size_t)b*16 + t] = a;
  }
}

extern "C" void kernel_launch(void* const* d_in, const int* in_sizes, int n_in,
                              void* d_out, int out_size, void* d_ws, size_t ws_size,
                              hipStream_t stream) {
  const float* input      = (const float*)d_in[0];
  const float* sse_w      = (const float*)d_in[1];
  const float* sse_b      = (const float*)d_in[2];
  const float* conv1_w    = (const float*)d_in[3];
  const float* conv1_b    = (const float*)d_in[4];
  const float* conv2_w    = (const float*)d_in[5];
  const float* conv2_b    = (const float*)d_in[6];
  const float* dense1_w   = (const float*)d_in[7];
  const float* dense1_b   = (const float*)d_in[8];
  const float* patch_w    = (const float*)d_in[9];
  const float* patch_b    = (const float*)d_in[10];
  const float* cls_token  = (const float*)d_in[11];
  const float* pos_emb    = (const float*)d_in[12];
  const float* ln1_g      = (const float*)d_in[13];
  const float* ln1_b      = (const float*)d_in[14];
  const float* qkv_w      = (const float*)d_in[15];
  const float* attn_out_w = (const float*)d_in[16];
  const float* attn_out_b = (const float*)d_in[17];
  const float* ln2_g      = (const float*)d_in[18];
  const float* ln2_b      = (const float*)d_in[19];
  const float* ff1_w      = (const float*)d_in[20];
  const float* ff1_b      = (const float*)d_in[21];
  const float* ff2_w      = (const float*)d_in[22];
  const float* ff2_b      = (const float*)d_in[23];
  const float* head_ln_g  = (const float*)d_in[24];
  const float* head_ln_b  = (const float*)d_in[25];
  const float* head_w     = (const float*)d_in[26];
  const float* head_b     = (const float*)d_in[27];
  float* out = (float*)d_out;

  // workspace layout (floats). conv scratch region is reused by transformer scratch.
  float* ws = (float*)d_ws;
  float* xs  = ws;                  // 3,840,000   scaled input
  float* y   = xs + 3840000;        // 32,768      conv-branch output
  float* x   = y + 32768;           // 9,863,168   tokens
  float* big = x + 9863168;
  float* c1  = big;                 // 21,676,032  conv1 out
  float* c2  = c1 + 21676032;       // 4,784,128   conv2 out
  float* xn  = big;                 // 9,863,168   ln1 out (reuses conv region)
  float* ao  = xn + 9863168;        // 9,863,168   attention out

  k_sse   <<<NB*25, 64, 0, stream>>>(input, sse_w, sse_b, xs);
  k_conv1 <<<NB*9, 256, 0, stream>>>(xs, conv1_w, conv1_b, c1);
  k_conv2 <<<NB*4, 256, 0, stream>>>(c1, conv2_w, conv2_b, c2);
  k_dense1<<<NB, 256, 0, stream>>>(c2, dense1_w, dense1_b, y);
  k_patch <<<NB*SEQ, 64, 0, stream>>>(xs, patch_w, patch_b, cls_token, pos_emb, x);
  for (int i = 0; i < 5; ++i) {
    k_ln     <<<NB*SEQ, 64, 0, stream>>>(x, ln1_g + i*64, ln1_b + i*64, xn);
    k_attn   <<<NB*4, 256, 0, stream>>>(xn, qkv_w + (size_t)i*192*64, ao);
    k_attnout<<<NB*SEQ, 64, 0, stream>>>(ao, attn_out_w + (size_t)i*4096, attn_out_b + i*64, x);
    k_ff     <<<NB*SEQ, 64, 0, stream>>>(x, ln2_g + i*64, ln2_b + i*64,
                 ff1_w + (size_t)i*512, ff1_b + i*8, ff2_w + (size_t)i*512, ff2_b + i*64);
  }
  k_head<<<NB, 128, 0, stream>>>(x, y, head_ln_g, head_ln_b, head_w, head_b, out);
}

// Round 2
// 6078.310 us; speedup vs baseline: 1.1676x; 1.1676x over previous
//
#include <hip/hip_runtime.h>
#include <cmath>

#define NB 512
#define SEQ 301
#define ATT_SCALE 0.25f

// ---------------- K1: SSE gate
__global__ __launch_bounds__(64) void k_sse(const float* __restrict__ xin,
    const float* __restrict__ sw, const float* __restrict__ sb, float* __restrict__ xs) {
  int blk = blockIdx.x; int b = blk / 25, p = blk % 25; int lane = threadIdx.x;
  const float* src = xin + (size_t)b*7500 + p*300;
  float s = 0.f;
  for (int c = lane; c < 300; c += 64) s += src[c]*sw[c];
  #pragma unroll
  for (int o = 32; o > 0; o >>= 1) s += __shfl_down(s, o, 64);
  s = __shfl(s, 0, 64);
  float sq = 1.f/(1.f + __expf(-(s + sb[0])));
  float* dst = xs + (size_t)b*7500 + p*300;
  for (int c = lane; c < 300; c += 64) dst[c] = src[c]*sq;
}

// ---------------- K2: conv1 (16,1,3,3,7) VALID -> (B,16,3,3,294) + relu
__global__ __launch_bounds__(256) void k_conv1(const float* __restrict__ xs,
    const float* __restrict__ w, const float* __restrict__ bias, float* __restrict__ c1) {
  int blk = blockIdx.x; int b = blk/9; int dh = blk%9; int d0 = dh/3, h0 = dh%3;
  __shared__ float in_s[2700];
  __shared__ float w_s[1008];
  int tid = threadIdx.x;
  for (int i = tid; i < 2700; i += 256) {
    int r = i/300, cc = i%300;
    int kd = r/3, kh = r%3;
    in_s[i] = xs[(size_t)b*7500 + (size_t)((d0+kd)*5 + (h0+kh))*300 + cc];
  }
  for (int i = tid; i < 1008; i += 256) w_s[i] = w[i];
  __syncthreads();
  for (int i = tid; i < 16*294; i += 256) {
    int o = i/294, wo = i%294;
    float acc = bias[o];
    const float* wp = &w_s[o*63];
    #pragma unroll
    for (int r = 0; r < 9; ++r) {
      const float* ip = &in_s[r*300 + wo];
      #pragma unroll
      for (int kw = 0; kw < 7; ++kw) acc += ip[kw]*wp[r*7 + kw];
    }
    c1[(((size_t)b*16 + o)*9 + dh)*294 + wo] = fmaxf(acc, 0.f);
  }
}

// ---------------- K3: conv2 (32,16,3,3,3) VALID -> (B,32,292) + relu
__global__ __launch_bounds__(256) void k_conv2(const float* __restrict__ c1,
    const float* __restrict__ w, const float* __restrict__ bias, float* __restrict__ c2) {
  int blk = blockIdx.x; int b = blk/4; int chunk = blk%4; int w0 = chunk*73;
  __shared__ float p_s[10800];
  int tid = threadIdx.x;
  for (int i = tid; i < 10800; i += 256) {
    int ci = i/675; int rem = i%675; int r = rem/75; int ww = rem%75;
    p_s[i] = c1[(((size_t)b*16 + ci)*9 + r)*294 + w0 + ww];
  }
  __syncthreads();
  for (int i = tid; i < 32*73; i += 256) {
    int o = i/73, w2 = i%73;
    float acc = bias[o];
    const float* wp = &w[(size_t)o*432];
    #pragma unroll
    for (int ci = 0; ci < 16; ++ci) {
      #pragma unroll
      for (int r = 0; r < 9; ++r) {
        const float* ip = &p_s[(ci*9 + r)*75 + w2];
        #pragma unroll
        for (int kw = 0; kw < 3; ++kw) acc += ip[kw]*wp[ci*27 + r*3 + kw];
      }
    }
    c2[((size_t)b*32 + o)*292 + w0 + w2] = fmaxf(acc, 0.f);
  }
}

// ---------------- K4: dense1
__global__ __launch_bounds__(256) void k_dense1(const float* __restrict__ c2,
    const float* __restrict__ w, const float* __restrict__ bias, float* __restrict__ y) {
  int b = blockIdx.x; int tid = threadIdx.x; int lane = tid & 63; int wv = tid >> 6;
  const float* xrow = c2 + (size_t)b*9344;
  float acc[16];
  #pragma unroll
  for (int o = 0; o < 16; ++o) acc[o] = 0.f;
  int obase = wv*16;
  for (int k = lane; k < 9344; k += 64) {
    float xv = xrow[k];
    #pragma unroll
    for (int o = 0; o < 16; ++o) acc[o] += xv * w[(size_t)(obase+o)*9344 + k];
  }
  #pragma unroll
  for (int o = 0; o < 16; ++o) {
    float s = acc[o];
    #pragma unroll
    for (int off = 32; off; off >>= 1) s += __shfl_down(s, off, 64);
    if (lane == 0) y[(size_t)b*64 + obase + o] = s + bias[obase+o];
  }
}

// ---------------- K5: patch embed + cls + pos (4 rows per block)
__global__ __launch_bounds__(256) void k_patch(const float* __restrict__ xs,
    const float* __restrict__ pw, const float* __restrict__ pb,
    const float* __restrict__ cls, const float* __restrict__ pos, float* __restrict__ x) {
  int row = blockIdx.x*4 + threadIdx.y;
  int b = row/SEQ; int s = row%SEQ; int d = threadIdx.x;
  float acc;
  if (s == 0) {
    acc = cls[d] + pos[d];
  } else {
    acc = pb[d] + pos[s*64 + d];
    const float* patch = xs + (size_t)b*7500 + (size_t)(s-1)*25;
    const float* wr = pw + d*25;
    #pragma unroll
    for (int p = 0; p < 25; ++p) acc += patch[p]*wr[p];
  }
  x[(size_t)row*64 + d] = acc;
}

// ---------------- K7: fused LN1 + per-(b,h) QKV + attention (thread-per-row)
__global__ __launch_bounds__(320) void k_attn(const float* __restrict__ x,
    const float* __restrict__ g, const float* __restrict__ bt,
    const float* __restrict__ qkvw, float* __restrict__ ao) {
  int blk = blockIdx.x; int b = blk >> 2; int h = blk & 3;
  __shared__ alignas(16) float K_s[SEQ*16];
  __shared__ alignas(16) float V_s[SEQ*16];
  int tid = threadIdx.x;
  bool active = tid < SEQ;
  int s = active ? tid : (SEQ-1);

  // --- load own row + LN1 (in registers)
  const float4* xr = (const float4*)(x + ((size_t)b*SEQ + s)*64);
  float4 xv[16];
  #pragma unroll
  for (int i = 0; i < 16; ++i) xv[i] = xr[i];
  float m = 0.f;
  #pragma unroll
  for (int i = 0; i < 16; ++i) m += xv[i].x + xv[i].y + xv[i].z + xv[i].w;
  m *= (1.f/64.f);
  float var = 0.f;
  #pragma unroll
  for (int i = 0; i < 16; ++i) {
    float a = xv[i].x - m, bb = xv[i].y - m, c = xv[i].z - m, dd = xv[i].w - m;
    var += a*a + bb*bb + c*c + dd*dd;
  }
  float rs = rsqrtf(var*(1.f/64.f) + 1e-5f);
  const float4* g4 = (const float4*)g;
  const float4* b4 = (const float4*)bt;
  #pragma unroll
  for (int i = 0; i < 16; ++i) {
    float4 gg = g4[i]; float4 bb = b4[i];
    xv[i].x = (xv[i].x - m)*rs*gg.x + bb.x;
    xv[i].y = (xv[i].y - m)*rs*gg.y + bb.y;
    xv[i].z = (xv[i].z - m)*rs*gg.z + bb.z;
    xv[i].w = (xv[i].w - m)*rs*gg.w + bb.w;
  }

  // --- QKV projection: weights are wave-uniform (scalar loads), x in regs
  const float4* wq = (const float4*)(qkvw + (size_t)(h*16)*64);
  const float4* wk = (const float4*)(qkvw + (size_t)(64 + h*16)*64);
  const float4* wv = (const float4*)(qkvw + (size_t)(128 + h*16)*64);
  float q[16], kk[16], vv[16];
  #pragma unroll
  for (int d = 0; d < 16; ++d) {
    float aq = 0.f, ak = 0.f, av = 0.f;
    #pragma unroll
    for (int j = 0; j < 16; ++j) {
      float4 xx = xv[j];
      float4 a = wq[d*16+j];
      float4 bq = wk[d*16+j];
      float4 c = wv[d*16+j];
      aq += xx.x*a.x + xx.y*a.y + xx.z*a.z + xx.w*a.w;
      ak += xx.x*bq.x + xx.y*bq.y + xx.z*bq.z + xx.w*bq.w;
      av += xx.x*c.x + xx.y*c.y + xx.z*c.z + xx.w*c.w;
    }
    q[d] = aq*ATT_SCALE; kk[d] = ak; vv[d] = av;
  }
  if (active) {
    #pragma unroll
    for (int i = 0; i < 4; ++i) {
      ((float4*)&K_s[s*16])[i] = ((float4*)kk)[i];
      ((float4*)&V_s[s*16])[i] = ((float4*)vv)[i];
    }
  }
  __syncthreads();

  // --- attention: scores are O(0.1) -> exp without max is safe
  float4 o0 = {0,0,0,0}, o1 = {0,0,0,0}, o2 = {0,0,0,0}, o3 = {0,0,0,0};
  float l = 0.f;
  const float4* q4 = (const float4*)q;
  float4 qa = q4[0], qb = q4[1], qc = q4[2], qd = q4[3];
  for (int j = 0; j < SEQ; ++j) {
    const float4* kp = (const float4*)&K_s[j*16];
    float4 k0 = kp[0], k1 = kp[1], k2 = kp[2], k3 = kp[3];
    const float4* vp = (const float4*)&V_s[j*16];
    float4 v0 = vp[0], v1 = vp[1], v2 = vp[2], v3 = vp[3];
    float d0 = qa.x*k0.x + qa.y*k0.y + qa.z*k0.z + qa.w*k0.w;
    float d1 = qb.x*k1.x + qb.y*k1.y + qb.z*k1.z + qb.w*k1.w;
    float d2 = qc.x*k2.x + qc.y*k2.y + qc.z*k2.z + qc.w*k2.w;
    float d3 = qd.x*k3.x + qd.y*k3.y + qd.z*k3.z + qd.w*k3.w;
    float p = __expf((d0 + d1) + (d2 + d3));
    l += p;
    o0.x += p*v0.x; o0.y += p*v0.y; o0.z += p*v0.z; o0.w += p*v0.w;
    o1.x += p*v1.x; o1.y += p*v1.y; o1.z += p*v1.z; o1.w += p*v1.w;
    o2.x += p*v2.x; o2.y += p*v2.y; o2.z += p*v2.z; o2.w += p*v2.w;
    o3.x += p*v3.x; o3.y += p*v3.y; o3.z += p*v3.z; o3.w += p*v3.w;
  }
  if (active) {
    float inv = 1.f/l;
    float4* dst = (float4*)(ao + ((size_t)b*SEQ + s)*64 + h*16);
    float4 r0 = {o0.x*inv, o0.y*inv, o0.z*inv, o0.w*inv};
    float4 r1 = {o1.x*inv, o1.y*inv, o1.z*inv, o1.w*inv};
    float4 r2 = {o2.x*inv, o2.y*inv, o2.z*inv, o2.w*inv};
    float4 r3 = {o3.x*inv, o3.y*inv, o3.z*inv, o3.w*inv};
    dst[0] = r0; dst[1] = r1; dst[2] = r2; dst[3] = r3;
  }
}

// ---------------- K8: fused attn-out proj + residual + LN2 + FF + residual (4 rows/block)
__global__ __launch_bounds__(256) void k_post(const float* __restrict__ ao,
    const float* __restrict__ w, const float* __restrict__ bias,
    const float* __restrict__ g, const float* __restrict__ bt,
    const float* __restrict__ w1, const float* __restrict__ b1,
    const float* __restrict__ w2, const float* __restrict__ b2,
    float* __restrict__ x) {
  int ty = threadIdx.y;
  int row = blockIdx.x*4 + ty;
  int d = threadIdx.x;
  __shared__ float o_s[4][64];
  __shared__ float xn_s[4][64];
  __shared__ float hid_s[4][8];
  o_s[ty][d] = ao[(size_t)row*64 + d];
  __syncthreads();
  float acc = bias[d];
  const float* wr = w + d*64;
  #pragma unroll 8
  for (int j = 0; j < 64; ++j) acc += o_s[ty][j]*wr[j];
  float v = x[(size_t)row*64 + d] + acc;
  // LN2 (wave = one row)
  float mm = v;
  #pragma unroll
  for (int o = 32; o; o >>= 1) mm += __shfl_down(mm, o, 64);
  mm = __shfl(mm, 0, 64) * (1.f/64.f);
  float c = v - mm;
  float s2 = c*c;
  #pragma unroll
  for (int o = 32; o; o >>= 1) s2 += __shfl_down(s2, o, 64);
  s2 = __shfl(s2, 0, 64) * (1.f/64.f);
  float xnv = c * rsqrtf(s2 + 1e-5f) * g[d] + bt[d];
  xn_s[ty][d] = xnv;
  __syncthreads();
  if (d < 8) {
    float a = b1[d];
    const float* w1r = w1 + d*64;
    #pragma unroll 8
    for (int j = 0; j < 64; ++j) a += xn_s[ty][j]*w1r[j];
    hid_s[ty][d] = 0.5f*a*(1.f + erff(a*0.70710678f));
  }
  __syncthreads();
  float acc2 = b2[d];
  const float* w2r = w2 + d*8;
  #pragma unroll
  for (int t = 0; t < 8; ++t) acc2 += hid_s[ty][t]*w2r[t];
  x[(size_t)row*64 + d] = v + acc2;
}

// ---------------- K10: head
__global__ __launch_bounds__(128) void k_head(const float* __restrict__ x,
    const float* __restrict__ y, const float* __restrict__ g, const float* __restrict__ bt,
    const float* __restrict__ hw, const float* __restrict__ hb, float* __restrict__ out) {
  int b = blockIdx.x; int t = threadIdx.x; int lane = t & 63; int wv = t >> 6;
  float v = (t < 64) ? x[(size_t)b*SEQ*64 + t] : y[(size_t)b*64 + t - 64];
  __shared__ float rbuf[2];
  __shared__ float z_s[128];
  float s = v;
  #pragma unroll
  for (int o = 32; o; o >>= 1) s += __shfl_down(s, o, 64);
  if (lane == 0) rbuf[wv] = s;
  __syncthreads();
  float m = (rbuf[0] + rbuf[1]) * (1.f/128.f);
  __syncthreads();
  float c = v - m;
  float s2 = c*c;
  #pragma unroll
  for (int o = 32; o; o >>= 1) s2 += __shfl_down(s2, o, 64);
  if (lane == 0) rbuf[wv] = s2;
  __syncthreads();
  float var = (rbuf[0] + rbuf[1]) * (1.f/128.f);
  z_s[t] = c * rsqrtf(var + 1e-5f) * g[t] + bt[t];
  __syncthreads();
  if (t < 16) {
    float a = hb[t];
    const float* wr = hw + t*128;
    #pragma unroll 8
    for (int j = 0; j < 128; ++j) a += z_s[j]*wr[j];
    out[(size_t)b*16 + t] = a;
  }
}

extern "C" void kernel_launch(void* const* d_in, const int* in_sizes, int n_in,
                              void* d_out, int out_size, void* d_ws, size_t ws_size,
                              hipStream_t stream) {
  const float* input      = (const float*)d_in[0];
  const float* sse_w      = (const float*)d_in[1];
  const float* sse_b      = (const float*)d_in[2];
  const float* conv1_w    = (const float*)d_in[3];
  const float* conv1_b    = (const float*)d_in[4];
  const float* conv2_w    = (const float*)d_in[5];
  const float* conv2_b    = (const float*)d_in[6];
  const float* dense1_w   = (const float*)d_in[7];
  const float* dense1_b   = (const float*)d_in[8];
  const float* patch_w    = (const float*)d_in[9];
  const float* patch_b    = (const float*)d_in[10];
  const float* cls_token  = (const float*)d_in[11];
  const float* pos_emb    = (const float*)d_in[12];
  const float* ln1_g      = (const float*)d_in[13];
  const float* ln1_b      = (const float*)d_in[14];
  const float* qkv_w      = (const float*)d_in[15];
  const float* attn_out_w = (const float*)d_in[16];
  const float* attn_out_b = (const float*)d_in[17];
  const float* ln2_g      = (const float*)d_in[18];
  const float* ln2_b      = (const float*)d_in[19];
  const float* ff1_w      = (const float*)d_in[20];
  const float* ff1_b      = (const float*)d_in[21];
  const float* ff2_w      = (const float*)d_in[22];
  const float* ff2_b      = (const float*)d_in[23];
  const float* head_ln_g  = (const float*)d_in[24];
  const float* head_ln_b  = (const float*)d_in[25];
  const float* head_w     = (const float*)d_in[26];
  const float* head_b     = (const float*)d_in[27];
  float* out = (float*)d_out;

  float* ws = (float*)d_ws;
  float* xs  = ws;                  // 3,840,000
  float* y   = xs + 3840000;        // 32,768
  float* x   = y + 32768;           // 9,863,168
  float* big = x + 9863168;
  float* c1  = big;                 // 21,676,032 (conv phase only)
  float* c2  = c1 + 21676032;       // 4,784,128  (conv phase only)
  float* ao  = big;                 // 9,863,168  (transformer phase, reuses c1)

  k_sse   <<<NB*25, 64, 0, stream>>>(input, sse_w, sse_b, xs);
  k_conv1 <<<NB*9, 256, 0, stream>>>(xs, conv1_w, conv1_b, c1);
  k_conv2 <<<NB*4, 256, 0, stream>>>(c1, conv2_w, conv2_b, c2);
  k_dense1<<<NB, 256, 0, stream>>>(c2, dense1_w, dense1_b, y);
  k_patch <<<NB*SEQ/4, dim3(64,4), 0, stream>>>(xs, patch_w, patch_b, cls_token, pos_emb, x);
  for (int i = 0; i < 5; ++i) {
    k_attn<<<NB*4, 320, 0, stream>>>(x, ln1_g + i*64, ln1_b + i*64,
                                     qkv_w + (size_t)i*192*64, ao);
    k_post<<<NB*SEQ/4, dim3(64,4), 0, stream>>>(ao,
                 attn_out_w + (size_t)i*4096, attn_out_b + i*64,
                 ln2_g + i*64, ln2_b + i*64,
                 ff1_w + (size_t)i*512, ff1_b + i*8, ff2_w + (size_t)i*512, ff2_b + i*64, x);
  }
  k_head<<<NB, 128, 0, stream>>>(x, y, head_ln_g, head_ln_b, head_w, head_b, out);
}

// Round 3
// 2954.888 us; speedup vs baseline: 2.4018x; 2.0570x over previous
//
#include <hip/hip_runtime.h>
#include <cmath>

#define NB 512
#define SEQ 301
#define ATT_SCALE 0.25f

using f32x4  = __attribute__((ext_vector_type(4))) float;
using s16x4  = __attribute__((ext_vector_type(4))) short;

__device__ __forceinline__ unsigned short f2bf(float f) {
  unsigned int u = __builtin_bit_cast(unsigned int, f);
  u += 0x7fffu + ((u >> 16) & 1u);
  return (unsigned short)(u >> 16);
}

__device__ __forceinline__ f32x4 mm16(s16x4 a, s16x4 b, f32x4 c) {
  return __builtin_amdgcn_mfma_f32_16x16x16bf16_1k(a, b, c, 0, 0, 0);
}

// ---------------- K1: SSE gate
__global__ __launch_bounds__(64) void k_sse(const float* __restrict__ xin,
    const float* __restrict__ sw, const float* __restrict__ sb, float* __restrict__ xs) {
  int blk = blockIdx.x; int b = blk / 25, p = blk % 25; int lane = threadIdx.x;
  const float* src = xin + (size_t)b*7500 + p*300;
  float s = 0.f;
  for (int c = lane; c < 300; c += 64) s += src[c]*sw[c];
  #pragma unroll
  for (int o = 32; o > 0; o >>= 1) s += __shfl_down(s, o, 64);
  s = __shfl(s, 0, 64);
  float sq = 1.f/(1.f + __expf(-(s + sb[0])));
  float* dst = xs + (size_t)b*7500 + p*300;
  for (int c = lane; c < 300; c += 64) dst[c] = src[c]*sq;
}

// ---------------- K2: conv1
__global__ __launch_bounds__(256) void k_conv1(const float* __restrict__ xs,
    const float* __restrict__ w, const float* __restrict__ bias, float* __restrict__ c1) {
  int blk = blockIdx.x; int b = blk/9; int dh = blk%9; int d0 = dh/3, h0 = dh%3;
  __shared__ float in_s[2700];
  __shared__ float w_s[1008];
  int tid = threadIdx.x;
  for (int i = tid; i < 2700; i += 256) {
    int r = i/300, cc = i%300;
    int kd = r/3, kh = r%3;
    in_s[i] = xs[(size_t)b*7500 + (size_t)((d0+kd)*5 + (h0+kh))*300 + cc];
  }
  for (int i = tid; i < 1008; i += 256) w_s[i] = w[i];
  __syncthreads();
  for (int i = tid; i < 16*294; i += 256) {
    int o = i/294, wo = i%294;
    float acc = bias[o];
    const float* wp = &w_s[o*63];
    #pragma unroll
    for (int r = 0; r < 9; ++r) {
      const float* ip = &in_s[r*300 + wo];
      #pragma unroll
      for (int kw = 0; kw < 7; ++kw) acc += ip[kw]*wp[r*7 + kw];
    }
    c1[(((size_t)b*16 + o)*9 + dh)*294 + wo] = fmaxf(acc, 0.f);
  }
}

// ---------------- K3: conv2
__global__ __launch_bounds__(256) void k_conv2(const float* __restrict__ c1,
    const float* __restrict__ w, const float* __restrict__ bias, float* __restrict__ c2) {
  int blk = blockIdx.x; int b = blk/4; int chunk = blk%4; int w0 = chunk*73;
  __shared__ float p_s[10800];
  int tid = threadIdx.x;
  for (int i = tid; i < 10800; i += 256) {
    int ci = i/675; int rem = i%675; int r = rem/75; int ww = rem%75;
    p_s[i] = c1[(((size_t)b*16 + ci)*9 + r)*294 + w0 + ww];
  }
  __syncthreads();
  for (int i = tid; i < 32*73; i += 256) {
    int o = i/73, w2 = i%73;
    float acc = bias[o];
    const float* wp = &w[(size_t)o*432];
    #pragma unroll
    for (int ci = 0; ci < 16; ++ci) {
      #pragma unroll
      for (int r = 0; r < 9; ++r) {
        const float* ip = &p_s[(ci*9 + r)*75 + w2];
        #pragma unroll
        for (int kw = 0; kw < 3; ++kw) acc += ip[kw]*wp[ci*27 + r*3 + kw];
      }
    }
    c2[((size_t)b*32 + o)*292 + w0 + w2] = fmaxf(acc, 0.f);
  }
}

// ---------------- K4: dense1
__global__ __launch_bounds__(256) void k_dense1(const float* __restrict__ c2,
    const float* __restrict__ w, const float* __restrict__ bias, float* __restrict__ y) {
  int b = blockIdx.x; int tid = threadIdx.x; int lane = tid & 63; int wv = tid >> 6;
  const float* xrow = c2 + (size_t)b*9344;
  float acc[16];
  #pragma unroll
  for (int o = 0; o < 16; ++o) acc[o] = 0.f;
  int obase = wv*16;
  for (int k = lane; k < 9344; k += 64) {
    float xv = xrow[k];
    #pragma unroll
    for (int o = 0; o < 16; ++o) acc[o] += xv * w[(size_t)(obase+o)*9344 + k];
  }
  #pragma unroll
  for (int o = 0; o < 16; ++o) {
    float s = acc[o];
    #pragma unroll
    for (int off = 32; off; off >>= 1) s += __shfl_down(s, off, 64);
    if (lane == 0) y[(size_t)b*64 + obase + o] = s + bias[obase+o];
  }
}

// ---------------- K5: patch embed + cls + pos
__global__ __launch_bounds__(256) void k_patch(const float* __restrict__ xs,
    const float* __restrict__ pw, const float* __restrict__ pb,
    const float* __restrict__ cls, const float* __restrict__ pos, float* __restrict__ x) {
  int row = blockIdx.x*4 + threadIdx.y;
  int b = row/SEQ; int s = row%SEQ; int d = threadIdx.x;
  float acc;
  if (s == 0) {
    acc = cls[d] + pos[d];
  } else {
    acc = pb[d] + pos[s*64 + d];
    const float* patch = xs + (size_t)b*7500 + (size_t)(s-1)*25;
    const float* wr = pw + d*25;
    #pragma unroll
    for (int p = 0; p < 25; ++p) acc += patch[p]*wr[p];
  }
  x[(size_t)row*64 + d] = acc;
}

// ---------------- K6: fused LN1 + QKV projection (MFMA), one block per batch b
// writes q_g,k_g: [(b*4+h)*304 + row]*16 + n   (bf16 rows)
//        vt_g:    [(b*4+h)*16 + d]*304 + key   (bf16, V transposed)
__global__ __launch_bounds__(256) void k_qkv(const float* __restrict__ x,
    const float* __restrict__ g, const float* __restrict__ bt,
    const float* __restrict__ qkvw,
    unsigned short* __restrict__ q_g, unsigned short* __restrict__ k_g,
    unsigned short* __restrict__ vt_g) {
  int b = blockIdx.x;
  int tid = threadIdx.x;
  int lane = tid & 63, wv = tid >> 6;
  int lm = lane & 15, lq = lane >> 4;
  __shared__ unsigned short xn_s[304*68];   // bf16, row stride 68

  // phase A: LN rows -> LDS bf16
  for (int rr = tid; rr < 304; rr += 256) {
    int src = rr < 301 ? rr : 300;
    const float4* xp = (const float4*)(x + ((size_t)b*SEQ + src)*64);
    float4 xv[16];
    #pragma unroll
    for (int i = 0; i < 16; ++i) xv[i] = xp[i];
    float m = 0.f;
    #pragma unroll
    for (int i = 0; i < 16; ++i) m += xv[i].x + xv[i].y + xv[i].z + xv[i].w;
    m *= (1.f/64.f);
    float var = 0.f;
    #pragma unroll
    for (int i = 0; i < 16; ++i) {
      float a = xv[i].x-m, bb = xv[i].y-m, c = xv[i].z-m, dd = xv[i].w-m;
      var += a*a + bb*bb + c*c + dd*dd;
    }
    float rs = rsqrtf(var*(1.f/64.f) + 1e-5f);
    const float4* g4 = (const float4*)g;
    const float4* b4 = (const float4*)bt;
    #pragma unroll
    for (int i = 0; i < 16; ++i) {
      float4 gg = g4[i]; float4 bb = b4[i];
      float e0 = (xv[i].x-m)*rs*gg.x + bb.x;
      float e1 = (xv[i].y-m)*rs*gg.y + bb.y;
      float e2 = (xv[i].z-m)*rs*gg.z + bb.z;
      float e3 = (xv[i].w-m)*rs*gg.w + bb.w;
      unsigned int u0 = (unsigned int)f2bf(e0) | ((unsigned int)f2bf(e1) << 16);
      unsigned int u1 = (unsigned int)f2bf(e2) | ((unsigned int)f2bf(e3) << 16);
      *(uint2*)&xn_s[rr*68 + i*4] = make_uint2(u0, u1);
    }
  }
  __syncthreads();

  // phase B: each wave owns 3 n-tiles (of 12): j = wv*3 + jj
  s16x4 Bf[3][4];
  int jidx[3];
  #pragma unroll
  for (int jj = 0; jj < 3; ++jj) {
    int j = wv*3 + jj; jidx[jj] = j;
    float scale = (j < 4) ? ATT_SCALE : 1.f;
    #pragma unroll
    for (int c = 0; c < 4; ++c) {
      float4 wf = *(const float4*)(qkvw + (size_t)(j*16 + lm)*64 + c*16 + lq*4);
      s16x4 bfv;
      bfv.x = (short)f2bf(wf.x*scale); bfv.y = (short)f2bf(wf.y*scale);
      bfv.z = (short)f2bf(wf.z*scale); bfv.w = (short)f2bf(wf.w*scale);
      Bf[jj][c] = bfv;
    }
  }
  for (int rt = 0; rt < 19; ++rt) {
    s16x4 Af[4];
    #pragma unroll
    for (int c = 0; c < 4; ++c)
      Af[c] = *(const s16x4*)&xn_s[(rt*16 + lm)*68 + c*16 + lq*4];
    #pragma unroll
    for (int jj = 0; jj < 3; ++jj) {
      f32x4 acc = {0.f,0.f,0.f,0.f};
      #pragma unroll
      for (int c = 0; c < 4; ++c) acc = mm16(Af[c], Bf[jj][c], acc);
      int j = jidx[jj]; int h = j & 3; int type = j >> 2;
      if (type < 2) {
        unsigned short* dst = (type == 0 ? q_g : k_g) + ((size_t)(b*4 + h)*304)*16;
        #pragma unroll
        for (int r = 0; r < 4; ++r) {
          int row = rt*16 + lq*4 + r;
          dst[row*16 + lm] = f2bf(acc[r]);
        }
      } else {
        unsigned int u0 = (unsigned int)f2bf(acc[0]) | ((unsigned int)f2bf(acc[1]) << 16);
        unsigned int u1 = (unsigned int)f2bf(acc[2]) | ((unsigned int)f2bf(acc[3]) << 16);
        *(uint2*)&vt_g[((size_t)(b*4 + h)*16 + lm)*304 + rt*16 + lq*4] = make_uint2(u0, u1);
      }
    }
  }
}

// ---------------- K7: MFMA attention, one block per (b,h)
__global__ __launch_bounds__(256) void k_attn(
    const unsigned short* __restrict__ q_g, const unsigned short* __restrict__ k_g,
    const unsigned short* __restrict__ vt_g, float* __restrict__ ao) {
  int bh = blockIdx.x; int b = bh >> 2, h = bh & 3;
  int tid = threadIdx.x;
  int lane = tid & 63, wv = tid >> 6;
  int lm = lane & 15, lq = lane >> 4;
  __shared__ unsigned short Ks[304*20];   // row stride 20 (40B)
  __shared__ unsigned short Qs[304*20];
  __shared__ unsigned short Vts[16*328];  // d-major, stride 328 (656B)

  // stage K, Q rows (16 bf16 each -> stride-20 rows)
  for (int i = tid; i < 304; i += 256) {
    const float4* kp = (const float4*)(k_g + ((size_t)bh*304 + i)*16);
    float4 a = kp[0], bb = kp[1];
    float2* d0 = (float2*)&Ks[i*20];
    d0[0] = make_float2(a.x, a.y);  d0[1] = make_float2(a.z, a.w);
    d0[2] = make_float2(bb.x, bb.y); d0[3] = make_float2(bb.z, bb.w);
    const float4* qp = (const float4*)(q_g + ((size_t)bh*304 + i)*16);
    float4 c = qp[0], dd = qp[1];
    float2* d1 = (float2*)&Qs[i*20];
    d1[0] = make_float2(c.x, c.y);  d1[1] = make_float2(c.z, c.w);
    d1[2] = make_float2(dd.x, dd.y); d1[3] = make_float2(dd.z, dd.w);
  }
  // stage V^T: 16 rows x 304 keys (38 granules of 16B)
  for (int i = tid; i < 16*38; i += 256) {
    int d = i / 38, gr = i % 38;
    float4 v = *(const float4*)(vt_g + ((size_t)bh*16 + d)*304 + gr*8);
    *(float4*)&Vts[d*328 + gr*8] = v;
  }
  __syncthreads();

  for (int qt = wv; qt < 19; qt += 4) {
    s16x4 qb = *(const s16x4*)&Qs[(qt*16 + lm)*20 + lq*4];
    f32x4 o = {0.f,0.f,0.f,0.f};
    float lsum = 0.f;
    #pragma unroll 2
    for (int kt = 0; kt < 18; ++kt) {
      s16x4 ka = *(const s16x4*)&Ks[(kt*16 + lm)*20 + lq*4];
      f32x4 zero = {0.f,0.f,0.f,0.f};
      f32x4 st = mm16(ka, qb, zero);
      float p0 = __expf(st[0]), p1 = __expf(st[1]), p2 = __expf(st[2]), p3 = __expf(st[3]);
      lsum += (p0 + p1) + (p2 + p3);
      s16x4 pa;
      pa.x = (short)f2bf(p0); pa.y = (short)f2bf(p1);
      pa.z = (short)f2bf(p2); pa.w = (short)f2bf(p3);
      s16x4 vb = *(const s16x4*)&Vts[lm*328 + kt*16 + lq*4];
      o = mm16(pa, vb, o);
    }
    { // kt = 18: keys 288..303, mask >= 301
      const int kt = 18;
      s16x4 ka = *(const s16x4*)&Ks[(kt*16 + lm)*20 + lq*4];
      f32x4 zero = {0.f,0.f,0.f,0.f};
      f32x4 st = mm16(ka, qb, zero);
      int kbase = kt*16 + lq*4;
      float p0 = (kbase + 0 < SEQ) ? __expf(st[0]) : 0.f;
      float p1 = (kbase + 1 < SEQ) ? __expf(st[1]) : 0.f;
      float p2 = (kbase + 2 < SEQ) ? __expf(st[2]) : 0.f;
      float p3 = (kbase + 3 < SEQ) ? __expf(st[3]) : 0.f;
      lsum += (p0 + p1) + (p2 + p3);
      s16x4 pa;
      pa.x = (short)f2bf(p0); pa.y = (short)f2bf(p1);
      pa.z = (short)f2bf(p2); pa.w = (short)f2bf(p3);
      s16x4 vb = *(const s16x4*)&Vts[lm*328 + kt*16 + lq*4];
      o = mm16(pa, vb, o);
    }
    lsum += __shfl_xor(lsum, 16, 64);
    lsum += __shfl_xor(lsum, 32, 64);
    float linv = 1.f / lsum;   // valid for q_local = lm
    #pragma unroll
    for (int r = 0; r < 4; ++r) {
      int q = qt*16 + lq*4 + r;
      float lr = __shfl(linv, lq*4 + r, 64);
      if (q < SEQ) ao[((size_t)b*SEQ + q)*64 + h*16 + lm] = o[r] * lr;
    }
  }
}

// ---------------- K8: fused attn-out proj + residual + LN2 + FF + residual
__global__ __launch_bounds__(256) void k_post(const float* __restrict__ ao,
    const float* __restrict__ w, const float* __restrict__ bias,
    const float* __restrict__ g, const float* __restrict__ bt,
    const float* __restrict__ w1, const float* __restrict__ b1,
    const float* __restrict__ w2, const float* __restrict__ b2,
    float* __restrict__ x) {
  int ty = threadIdx.y;
  int row = blockIdx.x*4 + ty;
  int d = threadIdx.x;
  __shared__ float o_s[4][64];
  __shared__ float xn_s[4][64];
  __shared__ float hid_s[4][8];
  o_s[ty][d] = ao[(size_t)row*64 + d];
  __syncthreads();
  float acc = bias[d];
  const float* wr = w + d*64;
  #pragma unroll 8
  for (int j = 0; j < 64; ++j) acc += o_s[ty][j]*wr[j];
  float v = x[(size_t)row*64 + d] + acc;
  float mm = v;
  #pragma unroll
  for (int o = 32; o; o >>= 1) mm += __shfl_down(mm, o, 64);
  mm = __shfl(mm, 0, 64) * (1.f/64.f);
  float c = v - mm;
  float s2 = c*c;
  #pragma unroll
  for (int o = 32; o; o >>= 1) s2 += __shfl_down(s2, o, 64);
  s2 = __shfl(s2, 0, 64) * (1.f/64.f);
  float xnv = c * rsqrtf(s2 + 1e-5f) * g[d] + bt[d];
  xn_s[ty][d] = xnv;
  __syncthreads();
  if (d < 8) {
    float a = b1[d];
    const float* w1r = w1 + d*64;
    #pragma unroll 8
    for (int j = 0; j < 64; ++j) a += xn_s[ty][j]*w1r[j];
    hid_s[ty][d] = 0.5f*a*(1.f + erff(a*0.70710678f));
  }
  __syncthreads();
  float acc2 = b2[d];
  const float* w2r = w2 + d*8;
  #pragma unroll
  for (int t = 0; t < 8; ++t) acc2 += hid_s[ty][t]*w2r[t];
  x[(size_t)row*64 + d] = v + acc2;
}

// ---------------- K10: head
__global__ __launch_bounds__(128) void k_head(const float* __restrict__ x,
    const float* __restrict__ y, const float* __restrict__ g, const float* __restrict__ bt,
    const float* __restrict__ hw, const float* __restrict__ hb, float* __restrict__ out) {
  int b = blockIdx.x; int t = threadIdx.x; int lane = t & 63; int wv = t >> 6;
  float v = (t < 64) ? x[(size_t)b*SEQ*64 + t] : y[(size_t)b*64 + t - 64];
  __shared__ float rbuf[2];
  __shared__ float z_s[128];
  float s = v;
  #pragma unroll
  for (int o = 32; o; o >>= 1) s += __shfl_down(s, o, 64);
  if (lane == 0) rbuf[wv] = s;
  __syncthreads();
  float m = (rbuf[0] + rbuf[1]) * (1.f/128.f);
  __syncthreads();
  float c = v - m;
  float s2 = c*c;
  #pragma unroll
  for (int o = 32; o; o >>= 1) s2 += __shfl_down(s2, o, 64);
  if (lane == 0) rbuf[wv] = s2;
  __syncthreads();
  float var = (rbuf[0] + rbuf[1]) * (1.f/128.f);
  z_s[t] = c * rsqrtf(var + 1e-5f) * g[t] + bt[t];
  __syncthreads();
  if (t < 16) {
    float a = hb[t];
    const float* wr = hw + t*128;
    #pragma unroll 8
    for (int j = 0; j < 128; ++j) a += z_s[j]*wr[j];
    out[(size_t)b*16 + t] = a;
  }
}

extern "C" void kernel_launch(void* const* d_in, const int* in_sizes, int n_in,
                              void* d_out, int out_size, void* d_ws, size_t ws_size,
                              hipStream_t stream) {
  const float* input      = (const float*)d_in[0];
  const float* sse_w      = (const float*)d_in[1];
  const float* sse_b      = (const float*)d_in[2];
  const float* conv1_w    = (const float*)d_in[3];
  const float* conv1_b    = (const float*)d_in[4];
  const float* conv2_w    = (const float*)d_in[5];
  const float* conv2_b    = (const float*)d_in[6];
  const float* dense1_w   = (const float*)d_in[7];
  const float* dense1_b   = (const float*)d_in[8];
  const float* patch_w    = (const float*)d_in[9];
  const float* patch_b    = (const float*)d_in[10];
  const float* cls_token  = (const float*)d_in[11];
  const float* pos_emb    = (const float*)d_in[12];
  const float* ln1_g      = (const float*)d_in[13];
  const float* ln1_b      = (const float*)d_in[14];
  const float* qkv_w      = (const float*)d_in[15];
  const float* attn_out_w = (const float*)d_in[16];
  const float* attn_out_b = (const float*)d_in[17];
  const float* ln2_g      = (const float*)d_in[18];
  const float* ln2_b      = (const float*)d_in[19];
  const float* ff1_w      = (const float*)d_in[20];
  const float* ff1_b      = (const float*)d_in[21];
  const float* ff2_w      = (const float*)d_in[22];
  const float* ff2_b      = (const float*)d_in[23];
  const float* head_ln_g  = (const float*)d_in[24];
  const float* head_ln_b  = (const float*)d_in[25];
  const float* head_w     = (const float*)d_in[26];
  const float* head_b     = (const float*)d_in[27];
  float* out = (float*)d_out;

  float* ws = (float*)d_ws;
  float* xs  = ws;                    // 3,840,000
  float* y   = xs + 3840000;          // 32,768
  float* x   = y + 32768;             // 9,863,168
  float* R   = x + 9863168;           // shared region (26,460,160 floats)
  // conv phase:
  float* c1  = R;                     // 21,676,032
  float* c2  = c1 + 21676032;         // 4,784,128
  // transformer phase (reuses R):
  float* ao  = R;                     // 9,863,168
  unsigned short* q_g  = (unsigned short*)(R + 9863168);  // 9,961,472 u16
  unsigned short* k_g  = q_g + 9961472;                   // 9,961,472 u16
  unsigned short* vt_g = k_g + 9961472;                   // 9,961,472 u16

  k_sse   <<<NB*25, 64, 0, stream>>>(input, sse_w, sse_b, xs);
  k_conv1 <<<NB*9, 256, 0, stream>>>(xs, conv1_w, conv1_b, c1);
  k_conv2 <<<NB*4, 256, 0, stream>>>(c1, conv2_w, conv2_b, c2);
  k_dense1<<<NB, 256, 0, stream>>>(c2, dense1_w, dense1_b, y);
  k_patch <<<NB*SEQ/4, dim3(64,4), 0, stream>>>(xs, patch_w, patch_b, cls_token, pos_emb, x);
  for (int i = 0; i < 5; ++i) {
    k_qkv <<<NB, 256, 0, stream>>>(x, ln1_g + i*64, ln1_b + i*64,
                                   qkv_w + (size_t)i*192*64, q_g, k_g, vt_g);
    k_attn<<<NB*4, 256, 0, stream>>>(q_g, k_g, vt_g, ao);
    k_post<<<NB*SEQ/4, dim3(64,4), 0, stream>>>(ao,
                 attn_out_w + (size_t)i*4096, attn_out_b + i*64,
                 ln2_g + i*64, ln2_b + i*64,
                 ff1_w + (size_t)i*512, ff1_b + i*8, ff2_w + (size_t)i*512, ff2_b + i*64, x);
  }
  k_head<<<NB, 128, 0, stream>>>(x, y, head_ln_g, head_ln_b, head_w, head_b, out);
}

// Round 4
// 1365.507 us; speedup vs baseline: 5.1974x; 2.1639x over previous
//
#include <hip/hip_runtime.h>
#include <cmath>

#define NB 512
#define SEQ 301
#define ATT_SCALE 0.25f

using f32x4  = __attribute__((ext_vector_type(4))) float;
using s16x4  = __attribute__((ext_vector_type(4))) short;

__device__ __forceinline__ unsigned short f2bf(float f) {
  unsigned int u = __builtin_bit_cast(unsigned int, f);
  u += 0x7fffu + ((u >> 16) & 1u);
  return (unsigned short)(u >> 16);
}

__device__ __forceinline__ f32x4 mm16(s16x4 a, s16x4 b, f32x4 c) {
  return __builtin_amdgcn_mfma_f32_16x16x16bf16_1k(a, b, c, 0, 0, 0);
}

// ---------------- K1: SSE gate
__global__ __launch_bounds__(64) void k_sse(const float* __restrict__ xin,
    const float* __restrict__ sw, const float* __restrict__ sb, float* __restrict__ xs) {
  int blk = blockIdx.x; int b = blk / 25, p = blk % 25; int lane = threadIdx.x;
  const float* src = xin + (size_t)b*7500 + p*300;
  float s = 0.f;
  for (int c = lane; c < 300; c += 64) s += src[c]*sw[c];
  #pragma unroll
  for (int o = 32; o > 0; o >>= 1) s += __shfl_down(s, o, 64);
  s = __shfl(s, 0, 64);
  float sq = 1.f/(1.f + __expf(-(s + sb[0])));
  float* dst = xs + (size_t)b*7500 + p*300;
  for (int c = lane; c < 300; c += 64) dst[c] = src[c]*sq;
}

// ---------------- K2: conv1
__global__ __launch_bounds__(256) void k_conv1(const float* __restrict__ xs,
    const float* __restrict__ w, const float* __restrict__ bias, float* __restrict__ c1) {
  int blk = blockIdx.x; int b = blk/9; int dh = blk%9; int d0 = dh/3, h0 = dh%3;
  __shared__ float in_s[2700];
  __shared__ float w_s[1008];
  int tid = threadIdx.x;
  for (int i = tid; i < 2700; i += 256) {
    int r = i/300, cc = i%300;
    int kd = r/3, kh = r%3;
    in_s[i] = xs[(size_t)b*7500 + (size_t)((d0+kd)*5 + (h0+kh))*300 + cc];
  }
  for (int i = tid; i < 1008; i += 256) w_s[i] = w[i];
  __syncthreads();
  for (int i = tid; i < 16*294; i += 256) {
    int o = i/294, wo = i%294;
    float acc = bias[o];
    const float* wp = &w_s[o*63];
    #pragma unroll
    for (int r = 0; r < 9; ++r) {
      const float* ip = &in_s[r*300 + wo];
      #pragma unroll
      for (int kw = 0; kw < 7; ++kw) acc += ip[kw]*wp[r*7 + kw];
    }
    c1[(((size_t)b*16 + o)*9 + dh)*294 + wo] = fmaxf(acc, 0.f);
  }
}

// ---------------- K3: conv2
__global__ __launch_bounds__(256) void k_conv2(const float* __restrict__ c1,
    const float* __restrict__ w, const float* __restrict__ bias, float* __restrict__ c2) {
  int blk = blockIdx.x; int b = blk/4; int chunk = blk%4; int w0 = chunk*73;
  __shared__ float p_s[10800];
  int tid = threadIdx.x;
  for (int i = tid; i < 10800; i += 256) {
    int ci = i/675; int rem = i%675; int r = rem/75; int ww = rem%75;
    p_s[i] = c1[(((size_t)b*16 + ci)*9 + r)*294 + w0 + ww];
  }
  __syncthreads();
  for (int i = tid; i < 32*73; i += 256) {
    int o = i/73, w2 = i%73;
    float acc = bias[o];
    const float* wp = &w[(size_t)o*432];
    #pragma unroll
    for (int ci = 0; ci < 16; ++ci) {
      #pragma unroll
      for (int r = 0; r < 9; ++r) {
        const float* ip = &p_s[(ci*9 + r)*75 + w2];
        #pragma unroll
        for (int kw = 0; kw < 3; ++kw) acc += ip[kw]*wp[ci*27 + r*3 + kw];
      }
    }
    c2[((size_t)b*32 + o)*292 + w0 + w2] = fmaxf(acc, 0.f);
  }
}

// ---------------- K4: dense1
__global__ __launch_bounds__(256) void k_dense1(const float* __restrict__ c2,
    const float* __restrict__ w, const float* __restrict__ bias, float* __restrict__ y) {
  int b = blockIdx.x; int tid = threadIdx.x; int lane = tid & 63; int wv = tid >> 6;
  const float* xrow = c2 + (size_t)b*9344;
  float acc[16];
  #pragma unroll
  for (int o = 0; o < 16; ++o) acc[o] = 0.f;
  int obase = wv*16;
  for (int k = lane; k < 9344; k += 64) {
    float xv = xrow[k];
    #pragma unroll
    for (int o = 0; o < 16; ++o) acc[o] += xv * w[(size_t)(obase+o)*9344 + k];
  }
  #pragma unroll
  for (int o = 0; o < 16; ++o) {
    float s = acc[o];
    #pragma unroll
    for (int off = 32; off; off >>= 1) s += __shfl_down(s, off, 64);
    if (lane == 0) y[(size_t)b*64 + obase + o] = s + bias[obase+o];
  }
}

// ---------------- K5: patch embed + cls + pos
__global__ __launch_bounds__(256) void k_patch(const float* __restrict__ xs,
    const float* __restrict__ pw, const float* __restrict__ pb,
    const float* __restrict__ cls, const float* __restrict__ pos, float* __restrict__ x) {
  int row = blockIdx.x*4 + threadIdx.y;
  int b = row/SEQ; int s = row%SEQ; int d = threadIdx.x;
  float acc;
  if (s == 0) {
    acc = cls[d] + pos[d];
  } else {
    acc = pb[d] + pos[s*64 + d];
    const float* patch = xs + (size_t)b*7500 + (size_t)(s-1)*25;
    const float* wr = pw + d*25;
    #pragma unroll
    for (int p = 0; p < 25; ++p) acc += patch[p]*wr[p];
  }
  x[(size_t)row*64 + d] = acc;
}

// ---------------- K6: fused LN1 + QKV projection (MFMA), one block per batch b
__global__ __launch_bounds__(256) void k_qkv(const float* __restrict__ x,
    const float* __restrict__ g, const float* __restrict__ bt,
    const float* __restrict__ qkvw,
    unsigned short* __restrict__ q_g, unsigned short* __restrict__ k_g,
    unsigned short* __restrict__ vt_g) {
  int b = blockIdx.x;
  int tid = threadIdx.x;
  int lane = tid & 63, wv = tid >> 6;
  int lm = lane & 15, lq = lane >> 4;
  __shared__ unsigned short xn_s[304*68];   // bf16, row stride 68

  for (int rr = tid; rr < 304; rr += 256) {
    int src = rr < 301 ? rr : 300;
    const float4* xp = (const float4*)(x + ((size_t)b*SEQ + src)*64);
    float4 xv[16];
    #pragma unroll
    for (int i = 0; i < 16; ++i) xv[i] = xp[i];
    float m = 0.f;
    #pragma unroll
    for (int i = 0; i < 16; ++i) m += xv[i].x + xv[i].y + xv[i].z + xv[i].w;
    m *= (1.f/64.f);
    float var = 0.f;
    #pragma unroll
    for (int i = 0; i < 16; ++i) {
      float a = xv[i].x-m, bb = xv[i].y-m, c = xv[i].z-m, dd = xv[i].w-m;
      var += a*a + bb*bb + c*c + dd*dd;
    }
    float rs = rsqrtf(var*(1.f/64.f) + 1e-5f);
    const float4* g4 = (const float4*)g;
    const float4* b4 = (const float4*)bt;
    #pragma unroll
    for (int i = 0; i < 16; ++i) {
      float4 gg = g4[i]; float4 bb = b4[i];
      float e0 = (xv[i].x-m)*rs*gg.x + bb.x;
      float e1 = (xv[i].y-m)*rs*gg.y + bb.y;
      float e2 = (xv[i].z-m)*rs*gg.z + bb.z;
      float e3 = (xv[i].w-m)*rs*gg.w + bb.w;
      unsigned int u0 = (unsigned int)f2bf(e0) | ((unsigned int)f2bf(e1) << 16);
      unsigned int u1 = (unsigned int)f2bf(e2) | ((unsigned int)f2bf(e3) << 16);
      *(uint2*)&xn_s[rr*68 + i*4] = make_uint2(u0, u1);
    }
  }
  __syncthreads();

  s16x4 Bf[3][4];
  int jidx[3];
  #pragma unroll
  for (int jj = 0; jj < 3; ++jj) {
    int j = wv*3 + jj; jidx[jj] = j;
    float scale = (j < 4) ? ATT_SCALE : 1.f;
    #pragma unroll
    for (int c = 0; c < 4; ++c) {
      float4 wf = *(const float4*)(qkvw + (size_t)(j*16 + lm)*64 + c*16 + lq*4);
      s16x4 bfv;
      bfv.x = (short)f2bf(wf.x*scale); bfv.y = (short)f2bf(wf.y*scale);
      bfv.z = (short)f2bf(wf.z*scale); bfv.w = (short)f2bf(wf.w*scale);
      Bf[jj][c] = bfv;
    }
  }
  for (int rt = 0; rt < 19; ++rt) {
    s16x4 Af[4];
    #pragma unroll
    for (int c = 0; c < 4; ++c)
      Af[c] = *(const s16x4*)&xn_s[(rt*16 + lm)*68 + c*16 + lq*4];
    #pragma unroll
    for (int jj = 0; jj < 3; ++jj) {
      f32x4 acc = {0.f,0.f,0.f,0.f};
      #pragma unroll
      for (int c = 0; c < 4; ++c) acc = mm16(Af[c], Bf[jj][c], acc);
      int j = jidx[jj]; int h = j & 3; int type = j >> 2;
      if (type < 2) {
        unsigned short* dst = (type == 0 ? q_g : k_g) + ((size_t)(b*4 + h)*304)*16;
        #pragma unroll
        for (int r = 0; r < 4; ++r) {
          int row = rt*16 + lq*4 + r;
          dst[row*16 + lm] = f2bf(acc[r]);
        }
      } else {
        unsigned int u0 = (unsigned int)f2bf(acc[0]) | ((unsigned int)f2bf(acc[1]) << 16);
        unsigned int u1 = (unsigned int)f2bf(acc[2]) | ((unsigned int)f2bf(acc[3]) << 16);
        *(uint2*)&vt_g[((size_t)(b*4 + h)*16 + lm)*304 + rt*16 + lq*4] = make_uint2(u0, u1);
      }
    }
  }
}

// ---------------- K7: MFMA attention, one block per (b,h)
__global__ __launch_bounds__(256) void k_attn(
    const unsigned short* __restrict__ q_g, const unsigned short* __restrict__ k_g,
    const unsigned short* __restrict__ vt_g, float* __restrict__ ao) {
  int bh = blockIdx.x; int b = bh >> 2, h = bh & 3;
  int tid = threadIdx.x;
  int lane = tid & 63, wv = tid >> 6;
  int lm = lane & 15, lq = lane >> 4;
  __shared__ unsigned short Ks[304*20];
  __shared__ unsigned short Qs[304*20];
  __shared__ unsigned short Vts[16*328];

  for (int i = tid; i < 304; i += 256) {
    const float4* kp = (const float4*)(k_g + ((size_t)bh*304 + i)*16);
    float4 a = kp[0], bb = kp[1];
    float2* d0 = (float2*)&Ks[i*20];
    d0[0] = make_float2(a.x, a.y);  d0[1] = make_float2(a.z, a.w);
    d0[2] = make_float2(bb.x, bb.y); d0[3] = make_float2(bb.z, bb.w);
    const float4* qp = (const float4*)(q_g + ((size_t)bh*304 + i)*16);
    float4 c = qp[0], dd = qp[1];
    float2* d1 = (float2*)&Qs[i*20];
    d1[0] = make_float2(c.x, c.y);  d1[1] = make_float2(c.z, c.w);
    d1[2] = make_float2(dd.x, dd.y); d1[3] = make_float2(dd.z, dd.w);
  }
  for (int i = tid; i < 16*38; i += 256) {
    int d = i / 38, gr = i % 38;
    float4 v = *(const float4*)(vt_g + ((size_t)bh*16 + d)*304 + gr*8);
    *(float4*)&Vts[d*328 + gr*8] = v;
  }
  __syncthreads();

  for (int qt = wv; qt < 19; qt += 4) {
    s16x4 qb = *(const s16x4*)&Qs[(qt*16 + lm)*20 + lq*4];
    f32x4 o = {0.f,0.f,0.f,0.f};
    float lsum = 0.f;
    #pragma unroll 2
    for (int kt = 0; kt < 18; ++kt) {
      s16x4 ka = *(const s16x4*)&Ks[(kt*16 + lm)*20 + lq*4];
      f32x4 zero = {0.f,0.f,0.f,0.f};
      f32x4 st = mm16(ka, qb, zero);
      float p0 = __expf(st[0]), p1 = __expf(st[1]), p2 = __expf(st[2]), p3 = __expf(st[3]);
      lsum += (p0 + p1) + (p2 + p3);
      s16x4 pa;
      pa.x = (short)f2bf(p0); pa.y = (short)f2bf(p1);
      pa.z = (short)f2bf(p2); pa.w = (short)f2bf(p3);
      s16x4 vb = *(const s16x4*)&Vts[lm*328 + kt*16 + lq*4];
      o = mm16(pa, vb, o);
    }
    {
      const int kt = 18;
      s16x4 ka = *(const s16x4*)&Ks[(kt*16 + lm)*20 + lq*4];
      f32x4 zero = {0.f,0.f,0.f,0.f};
      f32x4 st = mm16(ka, qb, zero);
      int kbase = kt*16 + lq*4;
      float p0 = (kbase + 0 < SEQ) ? __expf(st[0]) : 0.f;
      float p1 = (kbase + 1 < SEQ) ? __expf(st[1]) : 0.f;
      float p2 = (kbase + 2 < SEQ) ? __expf(st[2]) : 0.f;
      float p3 = (kbase + 3 < SEQ) ? __expf(st[3]) : 0.f;
      lsum += (p0 + p1) + (p2 + p3);
      s16x4 pa;
      pa.x = (short)f2bf(p0); pa.y = (short)f2bf(p1);
      pa.z = (short)f2bf(p2); pa.w = (short)f2bf(p3);
      s16x4 vb = *(const s16x4*)&Vts[lm*328 + kt*16 + lq*4];
      o = mm16(pa, vb, o);
    }
    lsum += __shfl_xor(lsum, 16, 64);
    lsum += __shfl_xor(lsum, 32, 64);
    float linv = 1.f / lsum;
    #pragma unroll
    for (int r = 0; r < 4; ++r) {
      int q = qt*16 + lq*4 + r;
      float lr = __shfl(linv, lq*4 + r, 64);
      if (q < SEQ) ao[((size_t)b*SEQ + q)*64 + h*16 + lm] = o[r] * lr;
    }
  }
}

// ---------------- K8: fused attn-out proj (MFMA) + residual + LN2 + FF + residual
// grid NB*4, 64 threads (1 wave). wave w0 of batch b owns row-tiles rt = w0, w0+4, ...
__global__ __launch_bounds__(64) void k_post(const float* __restrict__ ao,
    const float* __restrict__ w, const float* __restrict__ bias,
    const float* __restrict__ g, const float* __restrict__ bt,
    const float* __restrict__ w1, const float* __restrict__ b1,
    const float* __restrict__ w2, const float* __restrict__ b2,
    float* __restrict__ x) {
  int b = blockIdx.x >> 2; int w0 = blockIdx.x & 3;
  int lane = threadIdx.x;
  int lm = lane & 15, lq = lane >> 4;

  // B-frags: out[row][n] = sum_j ao[row][j]*w[n][j]
  s16x4 Bf[4][4];
  #pragma unroll
  for (int nt = 0; nt < 4; ++nt) {
    #pragma unroll
    for (int c = 0; c < 4; ++c) {
      float4 wf = *(const float4*)(w + (size_t)(nt*16 + lm)*64 + c*16 + lq*4);
      s16x4 t;
      t.x = (short)f2bf(wf.x); t.y = (short)f2bf(wf.y);
      t.z = (short)f2bf(wf.z); t.w = (short)f2bf(wf.w);
      Bf[nt][c] = t;
    }
  }
  float biasv[4], gv[4], btv[4], b2v[4];
  float w1r[8][4], w2r[4][8];
  #pragma unroll
  for (int nt = 0; nt < 4; ++nt) {
    biasv[nt] = bias[nt*16 + lm];
    gv[nt]    = g[nt*16 + lm];
    btv[nt]   = bt[nt*16 + lm];
    b2v[nt]   = b2[nt*16 + lm];
    #pragma unroll
    for (int t = 0; t < 8; ++t) w2r[nt][t] = w2[(nt*16 + lm)*8 + t];
  }
  #pragma unroll
  for (int t = 0; t < 8; ++t)
    #pragma unroll
    for (int nt = 0; nt < 4; ++nt) w1r[t][nt] = w1[t*64 + nt*16 + lm];

  for (int rt = w0; rt < 19; rt += 4) {
    int rsrc = rt*16 + lm; if (rsrc > 300) rsrc = 300;
    const float* arow = ao + ((size_t)b*SEQ + rsrc)*64;
    f32x4 acc[4];
    #pragma unroll
    for (int nt = 0; nt < 4; ++nt)
      acc[nt] = (f32x4){biasv[nt], biasv[nt], biasv[nt], biasv[nt]};
    #pragma unroll
    for (int c = 0; c < 4; ++c) {
      float4 av = *(const float4*)(arow + c*16 + lq*4);
      s16x4 af;
      af.x = (short)f2bf(av.x); af.y = (short)f2bf(av.y);
      af.z = (short)f2bf(av.z); af.w = (short)f2bf(av.w);
      #pragma unroll
      for (int nt = 0; nt < 4; ++nt) acc[nt] = mm16(af, Bf[nt][c], acc[nt]);
    }
    int row0 = rt*16 + lq*4;
    float v[4][4];  // [r][nt]
    #pragma unroll
    for (int r = 0; r < 4; ++r) {
      int row = row0 + r; int rs2 = row > 300 ? 300 : row;
      const float* xr = x + ((size_t)b*SEQ + rs2)*64;
      #pragma unroll
      for (int nt = 0; nt < 4; ++nt) v[r][nt] = acc[nt][r] + xr[nt*16 + lm];
    }
    #pragma unroll
    for (int r = 0; r < 4; ++r) {
      float s = (v[r][0] + v[r][1]) + (v[r][2] + v[r][3]);
      s += __shfl_xor(s, 1, 64); s += __shfl_xor(s, 2, 64);
      s += __shfl_xor(s, 4, 64); s += __shfl_xor(s, 8, 64);
      float m = s * (1.f/64.f);
      float c0 = v[r][0]-m, c1 = v[r][1]-m, c2 = v[r][2]-m, c3 = v[r][3]-m;
      float s2 = (c0*c0 + c1*c1) + (c2*c2 + c3*c3);
      s2 += __shfl_xor(s2, 1, 64); s2 += __shfl_xor(s2, 2, 64);
      s2 += __shfl_xor(s2, 4, 64); s2 += __shfl_xor(s2, 8, 64);
      float rs = rsqrtf(s2*(1.f/64.f) + 1e-5f);
      float xn0 = c0*rs*gv[0] + btv[0];
      float xn1 = c1*rs*gv[1] + btv[1];
      float xn2 = c2*rs*gv[2] + btv[2];
      float xn3 = c3*rs*gv[3] + btv[3];
      float hg[8];
      #pragma unroll
      for (int t = 0; t < 8; ++t) {
        float p = xn0*w1r[t][0] + xn1*w1r[t][1] + xn2*w1r[t][2] + xn3*w1r[t][3];
        p += __shfl_xor(p, 1, 64); p += __shfl_xor(p, 2, 64);
        p += __shfl_xor(p, 4, 64); p += __shfl_xor(p, 8, 64);
        float a = p + b1[t];
        hg[t] = 0.5f*a*(1.f + erff(a*0.70710678f));
      }
      int row = row0 + r;
      if (row < SEQ) {
        float* xw = x + ((size_t)b*SEQ + row)*64;
        #pragma unroll
        for (int nt = 0; nt < 4; ++nt) {
          float o = 0.f;
          #pragma unroll
          for (int t = 0; t < 8; ++t) o += hg[t]*w2r[nt][t];
          xw[nt*16 + lm] = v[r][nt] + o + b2v[nt];
        }
      }
    }
  }
}

// ---------------- K10: head
__global__ __launch_bounds__(128) void k_head(const float* __restrict__ x,
    const float* __restrict__ y, const float* __restrict__ g, const float* __restrict__ bt,
    const float* __restrict__ hw, const float* __restrict__ hb, float* __restrict__ out) {
  int b = blockIdx.x; int t = threadIdx.x; int lane = t & 63; int wv = t >> 6;
  float v = (t < 64) ? x[(size_t)b*SEQ*64 + t] : y[(size_t)b*64 + t - 64];
  __shared__ float rbuf[2];
  __shared__ float z_s[128];
  float s = v;
  #pragma unroll
  for (int o = 32; o; o >>= 1) s += __shfl_down(s, o, 64);
  if (lane == 0) rbuf[wv] = s;
  __syncthreads();
  float m = (rbuf[0] + rbuf[1]) * (1.f/128.f);
  __syncthreads();
  float c = v - m;
  float s2 = c*c;
  #pragma unroll
  for (int o = 32; o; o >>= 1) s2 += __shfl_down(s2, o, 64);
  if (lane == 0) rbuf[wv] = s2;
  __syncthreads();
  float var = (rbuf[0] + rbuf[1]) * (1.f/128.f);
  z_s[t] = c * rsqrtf(var + 1e-5f) * g[t] + bt[t];
  __syncthreads();
  if (t < 16) {
    float a = hb[t];
    const float* wr = hw + t*128;
    #pragma unroll 8
    for (int j = 0; j < 128; ++j) a += z_s[j]*wr[j];
    out[(size_t)b*16 + t] = a;
  }
}

extern "C" void kernel_launch(void* const* d_in, const int* in_sizes, int n_in,
                              void* d_out, int out_size, void* d_ws, size_t ws_size,
                              hipStream_t stream) {
  const float* input      = (const float*)d_in[0];
  const float* sse_w      = (const float*)d_in[1];
  const float* sse_b      = (const float*)d_in[2];
  const float* conv1_w    = (const float*)d_in[3];
  const float* conv1_b    = (const float*)d_in[4];
  const float* conv2_w    = (const float*)d_in[5];
  const float* conv2_b    = (const float*)d_in[6];
  const float* dense1_w   = (const float*)d_in[7];
  const float* dense1_b   = (const float*)d_in[8];
  const float* patch_w    = (const float*)d_in[9];
  const float* patch_b    = (const float*)d_in[10];
  const float* cls_token  = (const float*)d_in[11];
  const float* pos_emb    = (const float*)d_in[12];
  const float* ln1_g      = (const float*)d_in[13];
  const float* ln1_b      = (const float*)d_in[14];
  const float* qkv_w      = (const float*)d_in[15];
  const float* attn_out_w = (const float*)d_in[16];
  const float* attn_out_b = (const float*)d_in[17];
  const float* ln2_g      = (const float*)d_in[18];
  const float* ln2_b      = (const float*)d_in[19];
  const float* ff1_w      = (const float*)d_in[20];
  const float* ff1_b      = (const float*)d_in[21];
  const float* ff2_w      = (const float*)d_in[22];
  const float* ff2_b      = (const float*)d_in[23];
  const float* head_ln_g  = (const float*)d_in[24];
  const float* head_ln_b  = (const float*)d_in[25];
  const float* head_w     = (const float*)d_in[26];
  const float* head_b     = (const float*)d_in[27];
  float* out = (float*)d_out;

  float* ws = (float*)d_ws;
  float* xs  = ws;                    // 3,840,000
  float* y   = xs + 3840000;          // 32,768
  float* x   = y + 32768;             // 9,863,168
  float* R   = x + 9863168;           // shared region
  float* c1  = R;                     // conv phase: 21,676,032
  float* c2  = c1 + 21676032;         //             4,784,128
  float* ao  = R;                     // transformer phase
  unsigned short* q_g  = (unsigned short*)(R + 9863168);
  unsigned short* k_g  = q_g + 9961472;
  unsigned short* vt_g = k_g + 9961472;

  k_sse   <<<NB*25, 64, 0, stream>>>(input, sse_w, sse_b, xs);
  k_conv1 <<<NB*9, 256, 0, stream>>>(xs, conv1_w, conv1_b, c1);
  k_conv2 <<<NB*4, 256, 0, stream>>>(c1, conv2_w, conv2_b, c2);
  k_dense1<<<NB, 256, 0, stream>>>(c2, dense1_w, dense1_b, y);
  k_patch <<<NB*SEQ/4, dim3(64,4), 0, stream>>>(xs, patch_w, patch_b, cls_token, pos_emb, x);
  for (int i = 0; i < 5; ++i) {
    k_qkv <<<NB, 256, 0, stream>>>(x, ln1_g + i*64, ln1_b + i*64,
                                   qkv_w + (size_t)i*192*64, q_g, k_g, vt_g);
    k_attn<<<NB*4, 256, 0, stream>>>(q_g, k_g, vt_g, ao);
    k_post<<<NB*4, 64, 0, stream>>>(ao,
                 attn_out_w + (size_t)i*4096, attn_out_b + i*64,
                 ln2_g + i*64, ln2_b + i*64,
                 ff1_w + (size_t)i*512, ff1_b + i*8, ff2_w + (size_t)i*512, ff2_b + i*64, x);
  }
  k_head<<<NB, 128, 0, stream>>>(x, y, head_ln_g, head_ln_b, head_w, head_b, out);
}

// Round 5
// 1071.073 us; speedup vs baseline: 6.6261x; 1.2749x over previous
//
#include <hip/hip_runtime.h>
#include <cmath>

#define NB 512
#define SEQ 301
#define ATT_SCALE 0.25f

using f32x4  = __attribute__((ext_vector_type(4))) float;
using s16x4  = __attribute__((ext_vector_type(4))) short;

__device__ __forceinline__ unsigned short f2bf(float f) {
  unsigned int u = __builtin_bit_cast(unsigned int, f);
  u += 0x7fffu + ((u >> 16) & 1u);
  return (unsigned short)(u >> 16);
}

__device__ __forceinline__ f32x4 mm16(s16x4 a, s16x4 b, f32x4 c) {
  return __builtin_amdgcn_mfma_f32_16x16x16bf16_1k(a, b, c, 0, 0, 0);
}

// ---------------- K1: SSE gate
__global__ __launch_bounds__(64) void k_sse(const float* __restrict__ xin,
    const float* __restrict__ sw, const float* __restrict__ sb, float* __restrict__ xs) {
  int blk = blockIdx.x; int b = blk / 25, p = blk % 25; int lane = threadIdx.x;
  const float* src = xin + (size_t)b*7500 + p*300;
  float s = 0.f;
  for (int c = lane; c < 300; c += 64) s += src[c]*sw[c];
  #pragma unroll
  for (int o = 32; o > 0; o >>= 1) s += __shfl_down(s, o, 64);
  s = __shfl(s, 0, 64);
  float sq = 1.f/(1.f + __expf(-(s + sb[0])));
  float* dst = xs + (size_t)b*7500 + p*300;
  for (int c = lane; c < 300; c += 64) dst[c] = src[c]*sq;
}

// ---------------- K2: conv1 as MFMA implicit GEMM, one block per batch.
// M=16 (out ch, A=weights), N=294 (w positions, B=im2col from LDS), K=63 (pad 64).
// Output: bf16, transposed layout c1t[b][w][ci*9 + dh]  (row stride 144).
__global__ __launch_bounds__(256) void k_conv1(const float* __restrict__ xs,
    const float* __restrict__ w, const float* __restrict__ bias,
    unsigned short* __restrict__ c1t) {
  int b = blockIdx.x;
  int tid = threadIdx.x;
  int lane = tid & 63, wv = tid >> 6;
  int lm = lane & 15, lq = lane >> 4;
  __shared__ unsigned short xss[32*312];  // rows 0..24 = data, 25..31 zero; cols 300..311 zero

  // zero pad regions (disjoint from data region -> single barrier suffices)
  for (int i = tid; i < 7*312; i += 256) xss[25*312 + i] = 0;
  for (int i = tid; i < 25*12; i += 256) {
    int p = i/12, c = 300 + i%12;
    xss[p*312 + c] = 0;
  }
  const float* src = xs + (size_t)b*7500;
  for (int i = tid; i < 7500; i += 256) {
    int p = i/300, c = i%300;
    xss[p*312 + c] = f2bf(src[i]);
  }
  __syncthreads();

  // A-frags: weights, lane lm = output channel o. k = kc*16 + lq*4 + j; k==63 -> A=0
  s16x4 Af[4];
  int P[4][4];   // im2col LDS offset per (kc,j): (kd*5+kh)*312 + kw
  float bv[4];
  #pragma unroll
  for (int r = 0; r < 4; ++r) bv[r] = bias[lq*4 + r];
  #pragma unroll
  for (int kc = 0; kc < 4; ++kc) {
    short e[4];
    #pragma unroll
    for (int j = 0; j < 4; ++j) {
      int k = kc*16 + lq*4 + j;
      float wf = (k < 63) ? w[lm*63 + k] : 0.f;
      e[j] = (short)f2bf(wf);
      int r_ = k/7, kw_ = k - r_*7;    // k==63 -> r_=9 -> row offset 15 (zeroed row), A=0 anyway
      int kd = r_/3, kh = r_ - kd*3;
      P[kc][j] = (kd*5 + kh)*312 + kw_;
    }
    s16x4 a; a.x = e[0]; a.y = e[1]; a.z = e[2]; a.w = e[3];
    Af[kc] = a;
  }

  for (int idx = wv; idx < 171; idx += 4) {
    int dh = idx/19, pt = idx - dh*19;
    int d0 = dh/3, h0 = dh - d0*3;
    int base = (d0*5 + h0)*312 + pt*16 + lm;
    f32x4 acc = {bv[0], bv[1], bv[2], bv[3]};
    #pragma unroll
    for (int kc = 0; kc < 4; ++kc) {
      s16x4 Bf;
      Bf.x = (short)xss[base + P[kc][0]];
      Bf.y = (short)xss[base + P[kc][1]];
      Bf.z = (short)xss[base + P[kc][2]];
      Bf.w = (short)xss[base + P[kc][3]];
      acc = mm16(Af[kc], Bf, acc);
    }
    int w_ = pt*16 + lm;
    if (w_ < 294) {
      unsigned short* dst = c1t + (size_t)b*42336 + w_*144 + dh;
      #pragma unroll
      for (int r = 0; r < 4; ++r) {
        float v = fmaxf(acc[r], 0.f);
        dst[(lq*4 + r)*9] = f2bf(v);
      }
    }
  }
}

// ---------------- K3: conv2 as MFMA implicit GEMM, one block per batch.
// out[o2=32][w2=292] = sum_{kw=0..2} sum_{k=ci*9+r} c1t[w2+kw][k] * W'[kw][k][o2]
// M = w2 (A from c1t LDS), N = o2 (B = weights in regs), K = 3 x 144.
__global__ __launch_bounds__(256) void k_conv2(const unsigned short* __restrict__ c1t,
    const float* __restrict__ w, const float* __restrict__ bias, float* __restrict__ c2) {
  int b = blockIdx.x;
  int tid = threadIdx.x;
  int lane = tid & 63, wv = tid >> 6;
  int lm = lane & 15, lq = lane >> 4;
  __shared__ unsigned short c1s[308*148];   // rows 294..307 zero; stride 148 -> conflict-free
  __shared__ unsigned short wt_s[96*148];   // [kw*32 + o2][k=ci*9+r]

  const unsigned short* src = c1t + (size_t)b*42336;
  for (int i = tid; i < 294*36; i += 256) {          // 8B granules
    int row = i/36, gg = i - row*36;
    *(uint2*)&c1s[row*148 + gg*4] = *(const uint2*)&src[row*144 + gg*4];
  }
  for (int i = tid; i < 14*148; i += 256) c1s[294*148 + i] = 0;
  for (int i = tid; i < 13824; i += 256) {
    int kw_ = i/4608, rem = i - kw_*4608;
    int o2 = rem/144, k = rem - o2*144;
    int ci = k/9, r_ = k - ci*9;
    wt_s[(kw_*32 + o2)*148 + k] = f2bf(w[o2*432 + ci*27 + r_*3 + kw_]);
  }
  __syncthreads();

  s16x4 Bf[3][9][2];
  #pragma unroll
  for (int kw_ = 0; kw_ < 3; ++kw_)
    #pragma unroll
    for (int kc = 0; kc < 9; ++kc)
      #pragma unroll
      for (int ot = 0; ot < 2; ++ot)
        Bf[kw_][kc][ot] = *(const s16x4*)&wt_s[(kw_*32 + ot*16 + lm)*148 + kc*16 + lq*4];

  float bv0 = bias[lm], bv1 = bias[16 + lm];
  for (int pt = wv; pt < 19; pt += 4) {
    f32x4 a0 = {bv0, bv0, bv0, bv0};
    f32x4 a1 = {bv1, bv1, bv1, bv1};
    #pragma unroll
    for (int kw_ = 0; kw_ < 3; ++kw_) {
      int rowb = (pt*16 + lm + kw_)*148;
      #pragma unroll
      for (int kc = 0; kc < 9; ++kc) {
        s16x4 Aw = *(const s16x4*)&c1s[rowb + kc*16 + lq*4];
        a0 = mm16(Aw, Bf[kw_][kc][0], a0);
        a1 = mm16(Aw, Bf[kw_][kc][1], a1);
      }
    }
    float* dst = c2 + (size_t)b*9344;
    #pragma unroll
    for (int r = 0; r < 4; ++r) {
      int w2 = pt*16 + lq*4 + r;
      if (w2 < 292) {
        dst[lm*292 + w2]      = fmaxf(a0[r], 0.f);
        dst[(16+lm)*292 + w2] = fmaxf(a1[r], 0.f);
      }
    }
  }
}

// ---------------- K4: dense1
__global__ __launch_bounds__(256) void k_dense1(const float* __restrict__ c2,
    const float* __restrict__ w, const float* __restrict__ bias, float* __restrict__ y) {
  int b = blockIdx.x; int tid = threadIdx.x; int lane = tid & 63; int wv = tid >> 6;
  const float* xrow = c2 + (size_t)b*9344;
  float acc[16];
  #pragma unroll
  for (int o = 0; o < 16; ++o) acc[o] = 0.f;
  int obase = wv*16;
  for (int k = lane; k < 9344; k += 64) {
    float xv = xrow[k];
    #pragma unroll
    for (int o = 0; o < 16; ++o) acc[o] += xv * w[(size_t)(obase+o)*9344 + k];
  }
  #pragma unroll
  for (int o = 0; o < 16; ++o) {
    float s = acc[o];
    #pragma unroll
    for (int off = 32; off; off >>= 1) s += __shfl_down(s, off, 64);
    if (lane == 0) y[(size_t)b*64 + obase + o] = s + bias[obase+o];
  }
}

// ---------------- K5: patch embed + cls + pos
__global__ __launch_bounds__(256) void k_patch(const float* __restrict__ xs,
    const float* __restrict__ pw, const float* __restrict__ pb,
    const float* __restrict__ cls, const float* __restrict__ pos, float* __restrict__ x) {
  int row = blockIdx.x*4 + threadIdx.y;
  int b = row/SEQ; int s = row%SEQ; int d = threadIdx.x;
  float acc;
  if (s == 0) {
    acc = cls[d] + pos[d];
  } else {
    acc = pb[d] + pos[s*64 + d];
    const float* patch = xs + (size_t)b*7500 + (size_t)(s-1)*25;
    const float* wr = pw + d*25;
    #pragma unroll
    for (int p = 0; p < 25; ++p) acc += patch[p]*wr[p];
  }
  x[(size_t)row*64 + d] = acc;
}

// ---------------- K6: fused LN1 + QKV projection (MFMA), one block per batch b
__global__ __launch_bounds__(256) void k_qkv(const float* __restrict__ x,
    const float* __restrict__ g, const float* __restrict__ bt,
    const float* __restrict__ qkvw,
    unsigned short* __restrict__ q_g, unsigned short* __restrict__ k_g,
    unsigned short* __restrict__ vt_g) {
  int b = blockIdx.x;
  int tid = threadIdx.x;
  int lane = tid & 63, wv = tid >> 6;
  int lm = lane & 15, lq = lane >> 4;
  __shared__ unsigned short xn_s[304*68];   // bf16, row stride 68

  for (int rr = tid; rr < 304; rr += 256) {
    int src = rr < 301 ? rr : 300;
    const float4* xp = (const float4*)(x + ((size_t)b*SEQ + src)*64);
    float4 xv[16];
    #pragma unroll
    for (int i = 0; i < 16; ++i) xv[i] = xp[i];
    float m = 0.f;
    #pragma unroll
    for (int i = 0; i < 16; ++i) m += xv[i].x + xv[i].y + xv[i].z + xv[i].w;
    m *= (1.f/64.f);
    float var = 0.f;
    #pragma unroll
    for (int i = 0; i < 16; ++i) {
      float a = xv[i].x-m, bb = xv[i].y-m, c = xv[i].z-m, dd = xv[i].w-m;
      var += a*a + bb*bb + c*c + dd*dd;
    }
    float rs = rsqrtf(var*(1.f/64.f) + 1e-5f);
    const float4* g4 = (const float4*)g;
    const float4* b4 = (const float4*)bt;
    #pragma unroll
    for (int i = 0; i < 16; ++i) {
      float4 gg = g4[i]; float4 bb = b4[i];
      float e0 = (xv[i].x-m)*rs*gg.x + bb.x;
      float e1 = (xv[i].y-m)*rs*gg.y + bb.y;
      float e2 = (xv[i].z-m)*rs*gg.z + bb.z;
      float e3 = (xv[i].w-m)*rs*gg.w + bb.w;
      unsigned int u0 = (unsigned int)f2bf(e0) | ((unsigned int)f2bf(e1) << 16);
      unsigned int u1 = (unsigned int)f2bf(e2) | ((unsigned int)f2bf(e3) << 16);
      *(uint2*)&xn_s[rr*68 + i*4] = make_uint2(u0, u1);
    }
  }
  __syncthreads();

  s16x4 Bf[3][4];
  int jidx[3];
  #pragma unroll
  for (int jj = 0; jj < 3; ++jj) {
    int j = wv*3 + jj; jidx[jj] = j;
    float scale = (j < 4) ? ATT_SCALE : 1.f;
    #pragma unroll
    for (int c = 0; c < 4; ++c) {
      float4 wf = *(const float4*)(qkvw + (size_t)(j*16 + lm)*64 + c*16 + lq*4);
      s16x4 bfv;
      bfv.x = (short)f2bf(wf.x*scale); bfv.y = (short)f2bf(wf.y*scale);
      bfv.z = (short)f2bf(wf.z*scale); bfv.w = (short)f2bf(wf.w*scale);
      Bf[jj][c] = bfv;
    }
  }
  for (int rt = 0; rt < 19; ++rt) {
    s16x4 Af[4];
    #pragma unroll
    for (int c = 0; c < 4; ++c)
      Af[c] = *(const s16x4*)&xn_s[(rt*16 + lm)*68 + c*16 + lq*4];
    #pragma unroll
    for (int jj = 0; jj < 3; ++jj) {
      f32x4 acc = {0.f,0.f,0.f,0.f};
      #pragma unroll
      for (int c = 0; c < 4; ++c) acc = mm16(Af[c], Bf[jj][c], acc);
      int j = jidx[jj]; int h = j & 3; int type = j >> 2;
      if (type < 2) {
        unsigned short* dst = (type == 0 ? q_g : k_g) + ((size_t)(b*4 + h)*304)*16;
        #pragma unroll
        for (int r = 0; r < 4; ++r) {
          int row = rt*16 + lq*4 + r;
          dst[row*16 + lm] = f2bf(acc[r]);
        }
      } else {
        unsigned int u0 = (unsigned int)f2bf(acc[0]) | ((unsigned int)f2bf(acc[1]) << 16);
        unsigned int u1 = (unsigned int)f2bf(acc[2]) | ((unsigned int)f2bf(acc[3]) << 16);
        *(uint2*)&vt_g[((size_t)(b*4 + h)*16 + lm)*304 + rt*16 + lq*4] = make_uint2(u0, u1);
      }
    }
  }
}

// ---------------- K7: MFMA attention, one block per (b,h)
__global__ __launch_bounds__(256) void k_attn(
    const unsigned short* __restrict__ q_g, const unsigned short* __restrict__ k_g,
    const unsigned short* __restrict__ vt_g, float* __restrict__ ao) {
  int bh = blockIdx.x; int b = bh >> 2, h = bh & 3;
  int tid = threadIdx.x;
  int lane = tid & 63, wv = tid >> 6;
  int lm = lane & 15, lq = lane >> 4;
  __shared__ unsigned short Ks[304*20];
  __shared__ unsigned short Qs[304*20];
  __shared__ unsigned short Vts[16*328];

  for (int i = tid; i < 304; i += 256) {
    const float4* kp = (const float4*)(k_g + ((size_t)bh*304 + i)*16);
    float4 a = kp[0], bb = kp[1];
    float2* d0 = (float2*)&Ks[i*20];
    d0[0] = make_float2(a.x, a.y);  d0[1] = make_float2(a.z, a.w);
    d0[2] = make_float2(bb.x, bb.y); d0[3] = make_float2(bb.z, bb.w);
    const float4* qp = (const float4*)(q_g + ((size_t)bh*304 + i)*16);
    float4 c = qp[0], dd = qp[1];
    float2* d1 = (float2*)&Qs[i*20];
    d1[0] = make_float2(c.x, c.y);  d1[1] = make_float2(c.z, c.w);
    d1[2] = make_float2(dd.x, dd.y); d1[3] = make_float2(dd.z, dd.w);
  }
  for (int i = tid; i < 16*38; i += 256) {
    int d = i / 38, gr = i % 38;
    float4 v = *(const float4*)(vt_g + ((size_t)bh*16 + d)*304 + gr*8);
    *(float4*)&Vts[d*328 + gr*8] = v;
  }
  __syncthreads();

  for (int qt = wv; qt < 19; qt += 4) {
    s16x4 qb = *(const s16x4*)&Qs[(qt*16 + lm)*20 + lq*4];
    f32x4 o = {0.f,0.f,0.f,0.f};
    float lsum = 0.f;
    #pragma unroll 2
    for (int kt = 0; kt < 18; ++kt) {
      s16x4 ka = *(const s16x4*)&Ks[(kt*16 + lm)*20 + lq*4];
      f32x4 zero = {0.f,0.f,0.f,0.f};
      f32x4 st = mm16(ka, qb, zero);
      float p0 = __expf(st[0]), p1 = __expf(st[1]), p2 = __expf(st[2]), p3 = __expf(st[3]);
      lsum += (p0 + p1) + (p2 + p3);
      s16x4 pa;
      pa.x = (short)f2bf(p0); pa.y = (short)f2bf(p1);
      pa.z = (short)f2bf(p2); pa.w = (short)f2bf(p3);
      s16x4 vb = *(const s16x4*)&Vts[lm*328 + kt*16 + lq*4];
      o = mm16(pa, vb, o);
    }
    {
      const int kt = 18;
      s16x4 ka = *(const s16x4*)&Ks[(kt*16 + lm)*20 + lq*4];
      f32x4 zero = {0.f,0.f,0.f,0.f};
      f32x4 st = mm16(ka, qb, zero);
      int kbase = kt*16 + lq*4;
      float p0 = (kbase + 0 < SEQ) ? __expf(st[0]) : 0.f;
      float p1 = (kbase + 1 < SEQ) ? __expf(st[1]) : 0.f;
      float p2 = (kbase + 2 < SEQ) ? __expf(st[2]) : 0.f;
      float p3 = (kbase + 3 < SEQ) ? __expf(st[3]) : 0.f;
      lsum += (p0 + p1) + (p2 + p3);
      s16x4 pa;
      pa.x = (short)f2bf(p0); pa.y = (short)f2bf(p1);
      pa.z = (short)f2bf(p2); pa.w = (short)f2bf(p3);
      s16x4 vb = *(const s16x4*)&Vts[lm*328 + kt*16 + lq*4];
      o = mm16(pa, vb, o);
    }
    lsum += __shfl_xor(lsum, 16, 64);
    lsum += __shfl_xor(lsum, 32, 64);
    float linv = 1.f / lsum;
    #pragma unroll
    for (int r = 0; r < 4; ++r) {
      int q = qt*16 + lq*4 + r;
      float lr = __shfl(linv, lq*4 + r, 64);
      if (q < SEQ) ao[((size_t)b*SEQ + q)*64 + h*16 + lm] = o[r] * lr;
    }
  }
}

// ---------------- K8: fused attn-out proj (MFMA) + residual + LN2 + FF + residual
__global__ __launch_bounds__(64) void k_post(const float* __restrict__ ao,
    const float* __restrict__ w, const float* __restrict__ bias,
    const float* __restrict__ g, const float* __restrict__ bt,
    const float* __restrict__ w1, const float* __restrict__ b1,
    const float* __restrict__ w2, const float* __restrict__ b2,
    float* __restrict__ x) {
  int b = blockIdx.x >> 2; int w0 = blockIdx.x & 3;
  int lane = threadIdx.x;
  int lm = lane & 15, lq = lane >> 4;

  s16x4 Bf[4][4];
  #pragma unroll
  for (int nt = 0; nt < 4; ++nt) {
    #pragma unroll
    for (int c = 0; c < 4; ++c) {
      float4 wf = *(const float4*)(w + (size_t)(nt*16 + lm)*64 + c*16 + lq*4);
      s16x4 t;
      t.x = (short)f2bf(wf.x); t.y = (short)f2bf(wf.y);
      t.z = (short)f2bf(wf.z); t.w = (short)f2bf(wf.w);
      Bf[nt][c] = t;
    }
  }
  float biasv[4], gv[4], btv[4], b2v[4];
  float w1r[8][4], w2r[4][8];
  #pragma unroll
  for (int nt = 0; nt < 4; ++nt) {
    biasv[nt] = bias[nt*16 + lm];
    gv[nt]    = g[nt*16 + lm];
    btv[nt]   = bt[nt*16 + lm];
    b2v[nt]   = b2[nt*16 + lm];
    #pragma unroll
    for (int t = 0; t < 8; ++t) w2r[nt][t] = w2[(nt*16 + lm)*8 + t];
  }
  #pragma unroll
  for (int t = 0; t < 8; ++t)
    #pragma unroll
    for (int nt = 0; nt < 4; ++nt) w1r[t][nt] = w1[t*64 + nt*16 + lm];

  for (int rt = w0; rt < 19; rt += 4) {
    int rsrc = rt*16 + lm; if (rsrc > 300) rsrc = 300;
    const float* arow = ao + ((size_t)b*SEQ + rsrc)*64;
    f32x4 acc[4];
    #pragma unroll
    for (int nt = 0; nt < 4; ++nt)
      acc[nt] = (f32x4){biasv[nt], biasv[nt], biasv[nt], biasv[nt]};
    #pragma unroll
    for (int c = 0; c < 4; ++c) {
      float4 av = *(const float4*)(arow + c*16 + lq*4);
      s16x4 af;
      af.x = (short)f2bf(av.x); af.y = (short)f2bf(av.y);
      af.z = (short)f2bf(av.z); af.w = (short)f2bf(av.w);
      #pragma unroll
      for (int nt = 0; nt < 4; ++nt) acc[nt] = mm16(af, Bf[nt][c], acc[nt]);
    }
    int row0 = rt*16 + lq*4;
    float v[4][4];
    #pragma unroll
    for (int r = 0; r < 4; ++r) {
      int row = row0 + r; int rs2 = row > 300 ? 300 : row;
      const float* xr = x + ((size_t)b*SEQ + rs2)*64;
      #pragma unroll
      for (int nt = 0; nt < 4; ++nt) v[r][nt] = acc[nt][r] + xr[nt*16 + lm];
    }
    #pragma unroll
    for (int r = 0; r < 4; ++r) {
      float s = (v[r][0] + v[r][1]) + (v[r][2] + v[r][3]);
      s += __shfl_xor(s, 1, 64); s += __shfl_xor(s, 2, 64);
      s += __shfl_xor(s, 4, 64); s += __shfl_xor(s, 8, 64);
      float m = s * (1.f/64.f);
      float c0 = v[r][0]-m, c1 = v[r][1]-m, c2 = v[r][2]-m, c3 = v[r][3]-m;
      float s2 = (c0*c0 + c1*c1) + (c2*c2 + c3*c3);
      s2 += __shfl_xor(s2, 1, 64); s2 += __shfl_xor(s2, 2, 64);
      s2 += __shfl_xor(s2, 4, 64); s2 += __shfl_xor(s2, 8, 64);
      float rs = rsqrtf(s2*(1.f/64.f) + 1e-5f);
      float xn0 = c0*rs*gv[0] + btv[0];
      float xn1 = c1*rs*gv[1] + btv[1];
      float xn2 = c2*rs*gv[2] + btv[2];
      float xn3 = c3*rs*gv[3] + btv[3];
      float hg[8];
      #pragma unroll
      for (int t = 0; t < 8; ++t) {
        float p = xn0*w1r[t][0] + xn1*w1r[t][1] + xn2*w1r[t][2] + xn3*w1r[t][3];
        p += __shfl_xor(p, 1, 64); p += __shfl_xor(p, 2, 64);
        p += __shfl_xor(p, 4, 64); p += __shfl_xor(p, 8, 64);
        float a = p + b1[t];
        hg[t] = 0.5f*a*(1.f + erff(a*0.70710678f));
      }
      int row = row0 + r;
      if (row < SEQ) {
        float* xw = x + ((size_t)b*SEQ + row)*64;
        #pragma unroll
        for (int nt = 0; nt < 4; ++nt) {
          float o = 0.f;
          #pragma unroll
          for (int t = 0; t < 8; ++t) o += hg[t]*w2r[nt][t];
          xw[nt*16 + lm] = v[r][nt] + o + b2v[nt];
        }
      }
    }
  }
}

// ---------------- K10: head
__global__ __launch_bounds__(128) void k_head(const float* __restrict__ x,
    const float* __restrict__ y, const float* __restrict__ g, const float* __restrict__ bt,
    const float* __restrict__ hw, const float* __restrict__ hb, float* __restrict__ out) {
  int b = blockIdx.x; int t = threadIdx.x; int lane = t & 63; int wv = t >> 6;
  float v = (t < 64) ? x[(size_t)b*SEQ*64 + t] : y[(size_t)b*64 + t - 64];
  __shared__ float rbuf[2];
  __shared__ float z_s[128];
  float s = v;
  #pragma unroll
  for (int o = 32; o; o >>= 1) s += __shfl_down(s, o, 64);
  if (lane == 0) rbuf[wv] = s;
  __syncthreads();
  float m = (rbuf[0] + rbuf[1]) * (1.f/128.f);
  __syncthreads();
  float c = v - m;
  float s2 = c*c;
  #pragma unroll
  for (int o = 32; o; o >>= 1) s2 += __shfl_down(s2, o, 64);
  if (lane == 0) rbuf[wv] = s2;
  __syncthreads();
  float var = (rbuf[0] + rbuf[1]) * (1.f/128.f);
  z_s[t] = c * rsqrtf(var + 1e-5f) * g[t] + bt[t];
  __syncthreads();
  if (t < 16) {
    float a = hb[t];
    const float* wr = hw + t*128;
    #pragma unroll 8
    for (int j = 0; j < 128; ++j) a += z_s[j]*wr[j];
    out[(size_t)b*16 + t] = a;
  }
}

extern "C" void kernel_launch(void* const* d_in, const int* in_sizes, int n_in,
                              void* d_out, int out_size, void* d_ws, size_t ws_size,
                              hipStream_t stream) {
  const float* input      = (const float*)d_in[0];
  const float* sse_w      = (const float*)d_in[1];
  const float* sse_b      = (const float*)d_in[2];
  const float* conv1_w    = (const float*)d_in[3];
  const float* conv1_b    = (const float*)d_in[4];
  const float* conv2_w    = (const float*)d_in[5];
  const float* conv2_b    = (const float*)d_in[6];
  const float* dense1_w   = (const float*)d_in[7];
  const float* dense1_b   = (const float*)d_in[8];
  const float* patch_w    = (const float*)d_in[9];
  const float* patch_b    = (const float*)d_in[10];
  const float* cls_token  = (const float*)d_in[11];
  const float* pos_emb    = (const float*)d_in[12];
  const float* ln1_g      = (const float*)d_in[13];
  const float* ln1_b      = (const float*)d_in[14];
  const float* qkv_w      = (const float*)d_in[15];
  const float* attn_out_w = (const float*)d_in[16];
  const float* attn_out_b = (const float*)d_in[17];
  const float* ln2_g      = (const float*)d_in[18];
  const float* ln2_b      = (const float*)d_in[19];
  const float* ff1_w      = (const float*)d_in[20];
  const float* ff1_b      = (const float*)d_in[21];
  const float* ff2_w      = (const float*)d_in[22];
  const float* ff2_b      = (const float*)d_in[23];
  const float* head_ln_g  = (const float*)d_in[24];
  const float* head_ln_b  = (const float*)d_in[25];
  const float* head_w     = (const float*)d_in[26];
  const float* head_b     = (const float*)d_in[27];
  float* out = (float*)d_out;

  float* ws = (float*)d_ws;
  float* xs  = ws;                    // 3,840,000
  float* y   = xs + 3840000;          // 32,768
  float* x   = y + 32768;             // 9,863,168
  float* R   = x + 9863168;           // shared region (26,460,160 floats)
  // conv phase:
  unsigned short* c1t = (unsigned short*)R;       // 512*42336 u16 = 21,676,032 u16
  float* c2  = R + 21676032;                      // 4,784,128 floats (offset kept from R4)
  // transformer phase (reuses R, stream-ordered after conv consumers):
  float* ao  = R;
  unsigned short* q_g  = (unsigned short*)(R + 9863168);
  unsigned short* k_g  = q_g + 9961472;
  unsigned short* vt_g = k_g + 9961472;

  k_sse   <<<NB*25, 64, 0, stream>>>(input, sse_w, sse_b, xs);
  k_conv1 <<<NB, 256, 0, stream>>>(xs, conv1_w, conv1_b, c1t);
  k_conv2 <<<NB, 256, 0, stream>>>(c1t, conv2_w, conv2_b, c2);
  k_dense1<<<NB, 256, 0, stream>>>(c2, dense1_w, dense1_b, y);
  k_patch <<<NB*SEQ/4, dim3(64,4), 0, stream>>>(xs, patch_w, patch_b, cls_token, pos_emb, x);
  for (int i = 0; i < 5; ++i) {
    k_qkv <<<NB, 256, 0, stream>>>(x, ln1_g + i*64, ln1_b + i*64,
                                   qkv_w + (size_t)i*192*64, q_g, k_g, vt_g);
    k_attn<<<NB*4, 256, 0, stream>>>(q_g, k_g, vt_g, ao);
    k_post<<<NB*4, 64, 0, stream>>>(ao,
                 attn_out_w + (size_t)i*4096, attn_out_b + i*64,
                 ln2_g + i*64, ln2_b + i*64,
                 ff1_w + (size_t)i*512, ff1_b + i*8, ff2_w + (size_t)i*512, ff2_b + i*64, x);
  }
  k_head<<<NB, 128, 0, stream>>>(x, y, head_ln_g, head_ln_b, head_w, head_b, out);
}

// Round 6
// 1066.595 us; speedup vs baseline: 6.6539x; 1.0042x over previous
//
#include <hip/hip_runtime.h>
#include <cmath>

#define NB 512
#define SEQ 301
#define ATT_SCALE 0.25f

using f32x4  = __attribute__((ext_vector_type(4))) float;
using s16x4  = __attribute__((ext_vector_type(4))) short;

__device__ __forceinline__ unsigned short f2bf(float f) {
  unsigned int u = __builtin_bit_cast(unsigned int, f);
  u += 0x7fffu + ((u >> 16) & 1u);
  return (unsigned short)(u >> 16);
}

__device__ __forceinline__ f32x4 mm16(s16x4 a, s16x4 b, f32x4 c) {
  return __builtin_amdgcn_mfma_f32_16x16x16bf16_1k(a, b, c, 0, 0, 0);
}

// ---------------- K1: SSE gate
__global__ __launch_bounds__(64) void k_sse(const float* __restrict__ xin,
    const float* __restrict__ sw, const float* __restrict__ sb, float* __restrict__ xs) {
  int blk = blockIdx.x; int b = blk / 25, p = blk % 25; int lane = threadIdx.x;
  const float* src = xin + (size_t)b*7500 + p*300;
  float s = 0.f;
  for (int c = lane; c < 300; c += 64) s += src[c]*sw[c];
  #pragma unroll
  for (int o = 32; o > 0; o >>= 1) s += __shfl_down(s, o, 64);
  s = __shfl(s, 0, 64);
  float sq = 1.f/(1.f + __expf(-(s + sb[0])));
  float* dst = xs + (size_t)b*7500 + p*300;
  for (int c = lane; c < 300; c += 64) dst[c] = src[c]*sq;
}

// ---------------- K2: fused conv1+conv2, MFMA, conv1 output lives in LDS only.
// block = (batch, w-chunk of 73). LDS: xss 5.6KB + c1s 24.9KB + wt_s 28.4KB = 58.9KB.
__global__ __launch_bounds__(256) void k_conv12(const float* __restrict__ xs,
    const float* __restrict__ w1c, const float* __restrict__ b1c,
    const float* __restrict__ w2c, const float* __restrict__ b2c,
    float* __restrict__ c2) {
  int blk = blockIdx.x; int b = blk >> 2; int chunk = blk & 3;
  int w0 = chunk*73;
  int tid = threadIdx.x;
  int lane = tid & 63, wv = tid >> 6;
  int lm = lane & 15, lq = lane >> 4;
  __shared__ unsigned short xss[32*88];    // rows 25..31 zero, cols 81..87 zero
  __shared__ unsigned short c1s[84*148];   // conv1 out [w_local][ci*9+dh]; rows 75..83 zero
  __shared__ unsigned short wt_s[96*148];  // conv2 weights [kw*32+o2][ci*9+r]

  // stage input slice (bf16)
  const float* src = xs + (size_t)b*7500;
  for (int i = tid; i < 2025; i += 256) {
    int p = i/81, c = i - p*81;
    xss[p*88 + c] = f2bf(src[p*300 + w0 + c]);
  }
  for (int i = tid; i < 7*88; i += 256) xss[25*88 + i] = 0;
  for (int i = tid; i < 25*7; i += 256) { int p = i/7, c = 81 + i%7; xss[p*88 + c] = 0; }
  for (int i = tid; i < 9*148; i += 256) c1s[75*148 + i] = 0;
  // stage conv2 weights re-indexed
  for (int i = tid; i < 13824; i += 256) {
    int kw_ = i/4608, rem = i - kw_*4608;
    int o2 = rem/144, k = rem - o2*144;
    int ci = k/9, r_ = k - ci*9;
    wt_s[(kw_*32 + o2)*148 + k] = f2bf(w2c[o2*432 + ci*27 + r_*3 + kw_]);
  }

  // conv1 weight A-frags (lane lm = out channel ci), K=63 padded to 64 with zeros
  s16x4 Af[4]; int P[4][4]; float bv[4];
  #pragma unroll
  for (int r = 0; r < 4; ++r) bv[r] = b1c[lq*4 + r];
  #pragma unroll
  for (int kc = 0; kc < 4; ++kc) {
    short e[4];
    #pragma unroll
    for (int j = 0; j < 4; ++j) {
      int k = kc*16 + lq*4 + j;
      float wf = (k < 63) ? w1c[lm*63 + k] : 0.f;
      e[j] = (short)f2bf(wf);
      int r_ = k/7, kw_ = k - r_*7;   // k==63 -> row 15 (zero region), A=0 anyway
      int kd = r_/3, kh = r_ - kd*3;
      P[kc][j] = (kd*5 + kh)*88 + kw_;
    }
    s16x4 a; a.x = e[0]; a.y = e[1]; a.z = e[2]; a.w = e[3];
    Af[kc] = a;
  }
  __syncthreads();

  // conv1: 9 dh x 5 pt tiles -> c1s (relu'd, bf16)
  for (int idx = wv; idx < 45; idx += 4) {
    int dh = idx/5, pt = idx - dh*5;
    int d0 = dh/3, h0 = dh - d0*3;
    int base = (d0*5 + h0)*88 + pt*16 + lm;
    f32x4 acc = {bv[0], bv[1], bv[2], bv[3]};
    #pragma unroll
    for (int kc = 0; kc < 4; ++kc) {
      s16x4 Bf;
      Bf.x = (short)xss[base + P[kc][0]];
      Bf.y = (short)xss[base + P[kc][1]];
      Bf.z = (short)xss[base + P[kc][2]];
      Bf.w = (short)xss[base + P[kc][3]];
      acc = mm16(Af[kc], Bf, acc);
    }
    int lw = pt*16 + lm;
    if (lw < 75) {
      unsigned short* dst = c1s + lw*148 + dh;
      #pragma unroll
      for (int r = 0; r < 4; ++r)
        dst[(lq*4 + r)*9] = f2bf(fmaxf(acc[r], 0.f));
    }
  }
  __syncthreads();

  // conv2: K = 3 kw x 144, A = c1s rows (lane lm = w2), B = wt_s rows (lane lm = o2)
  float bvo0 = b2c[lm], bvo1 = b2c[16 + lm];
  for (int task = wv; task < 10; task += 4) {
    int pt = task >> 1, ot = task & 1;
    float bb = ot ? bvo1 : bvo0;
    f32x4 acc = {bb, bb, bb, bb};
    #pragma unroll
    for (int kw_ = 0; kw_ < 3; ++kw_) {
      int rowb = (pt*16 + lm + kw_)*148;
      int wrow = (kw_*32 + ot*16 + lm)*148;
      #pragma unroll
      for (int kc = 0; kc < 9; ++kc) {
        s16x4 Aw = *(const s16x4*)&c1s[rowb + kc*16 + lq*4];
        s16x4 Bw = *(const s16x4*)&wt_s[wrow + kc*16 + lq*4];
        acc = mm16(Aw, Bw, acc);
      }
    }
    float* dst = c2 + (size_t)b*9344 + (ot*16 + lm)*292;
    #pragma unroll
    for (int r = 0; r < 4; ++r) {
      int w2l = pt*16 + lq*4 + r;
      if (w2l < 73) dst[w0 + w2l] = fmaxf(acc[r], 0.f);
    }
  }
}

// ---------------- K4: dense1
__global__ __launch_bounds__(256) void k_dense1(const float* __restrict__ c2,
    const float* __restrict__ w, const float* __restrict__ bias, float* __restrict__ y) {
  int b = blockIdx.x; int tid = threadIdx.x; int lane = tid & 63; int wv = tid >> 6;
  const float* xrow = c2 + (size_t)b*9344;
  float acc[16];
  #pragma unroll
  for (int o = 0; o < 16; ++o) acc[o] = 0.f;
  int obase = wv*16;
  for (int k = lane; k < 9344; k += 64) {
    float xv = xrow[k];
    #pragma unroll
    for (int o = 0; o < 16; ++o) acc[o] += xv * w[(size_t)(obase+o)*9344 + k];
  }
  #pragma unroll
  for (int o = 0; o < 16; ++o) {
    float s = acc[o];
    #pragma unroll
    for (int off = 32; off; off >>= 1) s += __shfl_down(s, off, 64);
    if (lane == 0) y[(size_t)b*64 + obase + o] = s + bias[obase+o];
  }
}

// ---------------- K5: patch embed + cls + pos
__global__ __launch_bounds__(256) void k_patch(const float* __restrict__ xs,
    const float* __restrict__ pw, const float* __restrict__ pb,
    const float* __restrict__ cls, const float* __restrict__ pos, float* __restrict__ x) {
  int row = blockIdx.x*4 + threadIdx.y;
  int b = row/SEQ; int s = row%SEQ; int d = threadIdx.x;
  float acc;
  if (s == 0) {
    acc = cls[d] + pos[d];
  } else {
    acc = pb[d] + pos[s*64 + d];
    const float* patch = xs + (size_t)b*7500 + (size_t)(s-1)*25;
    const float* wr = pw + d*25;
    #pragma unroll
    for (int p = 0; p < 25; ++p) acc += patch[p]*wr[p];
  }
  x[(size_t)row*64 + d] = acc;
}

// ---------------- K6: fused LN1 + QKV projection (MFMA), one block per batch b
// q_g,k_g: [bh][token][16] bf16 (coalesced via swapped-operand MFMA); vt_g: [bh][d][304]
__global__ __launch_bounds__(256) void k_qkv(const float* __restrict__ x,
    const float* __restrict__ g, const float* __restrict__ bt,
    const float* __restrict__ qkvw,
    unsigned short* __restrict__ q_g, unsigned short* __restrict__ k_g,
    unsigned short* __restrict__ vt_g) {
  int b = blockIdx.x;
  int tid = threadIdx.x;
  int lane = tid & 63, wv = tid >> 6;
  int lm = lane & 15, lq = lane >> 4;
  __shared__ unsigned short xn_s[304*68];   // bf16, row stride 68

  for (int rr = tid; rr < 304; rr += 256) {
    int src = rr < 301 ? rr : 300;
    const float4* xp = (const float4*)(x + ((size_t)b*SEQ + src)*64);
    float4 xv[16];
    #pragma unroll
    for (int i = 0; i < 16; ++i) xv[i] = xp[i];
    float m = 0.f;
    #pragma unroll
    for (int i = 0; i < 16; ++i) m += xv[i].x + xv[i].y + xv[i].z + xv[i].w;
    m *= (1.f/64.f);
    float var = 0.f;
    #pragma unroll
    for (int i = 0; i < 16; ++i) {
      float a = xv[i].x-m, bb = xv[i].y-m, c = xv[i].z-m, dd = xv[i].w-m;
      var += a*a + bb*bb + c*c + dd*dd;
    }
    float rs = rsqrtf(var*(1.f/64.f) + 1e-5f);
    const float4* g4 = (const float4*)g;
    const float4* b4 = (const float4*)bt;
    #pragma unroll
    for (int i = 0; i < 16; ++i) {
      float4 gg = g4[i]; float4 bb = b4[i];
      float e0 = (xv[i].x-m)*rs*gg.x + bb.x;
      float e1 = (xv[i].y-m)*rs*gg.y + bb.y;
      float e2 = (xv[i].z-m)*rs*gg.z + bb.z;
      float e3 = (xv[i].w-m)*rs*gg.w + bb.w;
      unsigned int u0 = (unsigned int)f2bf(e0) | ((unsigned int)f2bf(e1) << 16);
      unsigned int u1 = (unsigned int)f2bf(e2) | ((unsigned int)f2bf(e3) << 16);
      *(uint2*)&xn_s[rr*68 + i*4] = make_uint2(u0, u1);
    }
  }
  __syncthreads();

  s16x4 Bf[3][4];
  int jidx[3];
  #pragma unroll
  for (int jj = 0; jj < 3; ++jj) {
    int j = wv*3 + jj; jidx[jj] = j;
    float scale = (j < 4) ? ATT_SCALE : 1.f;
    #pragma unroll
    for (int c = 0; c < 4; ++c) {
      float4 wf = *(const float4*)(qkvw + (size_t)(j*16 + lm)*64 + c*16 + lq*4);
      s16x4 bfv;
      bfv.x = (short)f2bf(wf.x*scale); bfv.y = (short)f2bf(wf.y*scale);
      bfv.z = (short)f2bf(wf.z*scale); bfv.w = (short)f2bf(wf.w*scale);
      Bf[jj][c] = bfv;
    }
  }
  for (int rt = 0; rt < 19; ++rt) {
    s16x4 Af[4];
    #pragma unroll
    for (int c = 0; c < 4; ++c)
      Af[c] = *(const s16x4*)&xn_s[(rt*16 + lm)*68 + c*16 + lq*4];
    #pragma unroll
    for (int jj = 0; jj < 3; ++jj) {
      int j = jidx[jj]; int h = j & 3; int type = j >> 2;
      if (type < 2) {
        // swapped operands: D[m=d][n=token] -> lane lm = token, reg r = d
        f32x4 acc = {0.f,0.f,0.f,0.f};
        #pragma unroll
        for (int c = 0; c < 4; ++c) acc = mm16(Bf[jj][c], Af[c], acc);
        unsigned short* dst = (type == 0 ? q_g : k_g) + (size_t)(b*4 + h)*304*16;
        unsigned int u0 = (unsigned int)f2bf(acc[0]) | ((unsigned int)f2bf(acc[1]) << 16);
        unsigned int u1 = (unsigned int)f2bf(acc[2]) | ((unsigned int)f2bf(acc[3]) << 16);
        *(uint2*)&dst[(rt*16 + lm)*16 + lq*4] = make_uint2(u0, u1);
      } else {
        f32x4 acc = {0.f,0.f,0.f,0.f};
        #pragma unroll
        for (int c = 0; c < 4; ++c) acc = mm16(Af[c], Bf[jj][c], acc);
        unsigned int u0 = (unsigned int)f2bf(acc[0]) | ((unsigned int)f2bf(acc[1]) << 16);
        unsigned int u1 = (unsigned int)f2bf(acc[2]) | ((unsigned int)f2bf(acc[3]) << 16);
        *(uint2*)&vt_g[((size_t)(b*4 + h)*16 + lm)*304 + rt*16 + lq*4] = make_uint2(u0, u1);
      }
    }
  }
}

// ---------------- K7: MFMA attention, one block per (b,h)
__global__ __launch_bounds__(256) void k_attn(
    const unsigned short* __restrict__ q_g, const unsigned short* __restrict__ k_g,
    const unsigned short* __restrict__ vt_g, float* __restrict__ ao) {
  int bh = blockIdx.x; int b = bh >> 2, h = bh & 3;
  int tid = threadIdx.x;
  int lane = tid & 63, wv = tid >> 6;
  int lm = lane & 15, lq = lane >> 4;
  __shared__ unsigned short Ks[304*20];
  __shared__ unsigned short Qs[304*20];
  __shared__ unsigned short Vts[16*328];

  for (int i = tid; i < 304; i += 256) {
    const float4* kp = (const float4*)(k_g + ((size_t)bh*304 + i)*16);
    float4 a = kp[0], bb = kp[1];
    float2* d0 = (float2*)&Ks[i*20];
    d0[0] = make_float2(a.x, a.y);  d0[1] = make_float2(a.z, a.w);
    d0[2] = make_float2(bb.x, bb.y); d0[3] = make_float2(bb.z, bb.w);
    const float4* qp = (const float4*)(q_g + ((size_t)bh*304 + i)*16);
    float4 c = qp[0], dd = qp[1];
    float2* d1 = (float2*)&Qs[i*20];
    d1[0] = make_float2(c.x, c.y);  d1[1] = make_float2(c.z, c.w);
    d1[2] = make_float2(dd.x, dd.y); d1[3] = make_float2(dd.z, dd.w);
  }
  for (int i = tid; i < 16*38; i += 256) {
    int d = i / 38, gr = i % 38;
    float4 v = *(const float4*)(vt_g + ((size_t)bh*16 + d)*304 + gr*8);
    *(float4*)&Vts[d*328 + gr*8] = v;
  }
  __syncthreads();

  for (int qt = wv; qt < 19; qt += 4) {
    s16x4 qb = *(const s16x4*)&Qs[(qt*16 + lm)*20 + lq*4];
    f32x4 o = {0.f,0.f,0.f,0.f};
    float lsum = 0.f;
    #pragma unroll 2
    for (int kt = 0; kt < 18; ++kt) {
      s16x4 ka = *(const s16x4*)&Ks[(kt*16 + lm)*20 + lq*4];
      f32x4 zero = {0.f,0.f,0.f,0.f};
      f32x4 st = mm16(ka, qb, zero);
      float p0 = __expf(st[0]), p1 = __expf(st[1]), p2 = __expf(st[2]), p3 = __expf(st[3]);
      lsum += (p0 + p1) + (p2 + p3);
      s16x4 pa;
      pa.x = (short)f2bf(p0); pa.y = (short)f2bf(p1);
      pa.z = (short)f2bf(p2); pa.w = (short)f2bf(p3);
      s16x4 vb = *(const s16x4*)&Vts[lm*328 + kt*16 + lq*4];
      o = mm16(pa, vb, o);
    }
    {
      const int kt = 18;
      s16x4 ka = *(const s16x4*)&Ks[(kt*16 + lm)*20 + lq*4];
      f32x4 zero = {0.f,0.f,0.f,0.f};
      f32x4 st = mm16(ka, qb, zero);
      int kbase = kt*16 + lq*4;
      float p0 = (kbase + 0 < SEQ) ? __expf(st[0]) : 0.f;
      float p1 = (kbase + 1 < SEQ) ? __expf(st[1]) : 0.f;
      float p2 = (kbase + 2 < SEQ) ? __expf(st[2]) : 0.f;
      float p3 = (kbase + 3 < SEQ) ? __expf(st[3]) : 0.f;
      lsum += (p0 + p1) + (p2 + p3);
      s16x4 pa;
      pa.x = (short)f2bf(p0); pa.y = (short)f2bf(p1);
      pa.z = (short)f2bf(p2); pa.w = (short)f2bf(p3);
      s16x4 vb = *(const s16x4*)&Vts[lm*328 + kt*16 + lq*4];
      o = mm16(pa, vb, o);
    }
    lsum += __shfl_xor(lsum, 16, 64);
    lsum += __shfl_xor(lsum, 32, 64);
    float linv = 1.f / lsum;
    #pragma unroll
    for (int r = 0; r < 4; ++r) {
      int q = qt*16 + lq*4 + r;
      float lr = __shfl(linv, lq*4 + r, 64);
      if (q < SEQ) ao[((size_t)b*SEQ + q)*64 + h*16 + lm] = o[r] * lr;
    }
  }
}

// ---------------- K8: fused attn-out proj (MFMA) + residual + LN2 + FF + residual
__global__ __launch_bounds__(64) void k_post(const float* __restrict__ ao,
    const float* __restrict__ w, const float* __restrict__ bias,
    const float* __restrict__ g, const float* __restrict__ bt,
    const float* __restrict__ w1, const float* __restrict__ b1,
    const float* __restrict__ w2, const float* __restrict__ b2,
    float* __restrict__ x) {
  int b = blockIdx.x >> 2; int w0 = blockIdx.x & 3;
  int lane = threadIdx.x;
  int lm = lane & 15, lq = lane >> 4;

  s16x4 Bf[4][4];
  #pragma unroll
  for (int nt = 0; nt < 4; ++nt) {
    #pragma unroll
    for (int c = 0; c < 4; ++c) {
      float4 wf = *(const float4*)(w + (size_t)(nt*16 + lm)*64 + c*16 + lq*4);
      s16x4 t;
      t.x = (short)f2bf(wf.x); t.y = (short)f2bf(wf.y);
      t.z = (short)f2bf(wf.z); t.w = (short)f2bf(wf.w);
      Bf[nt][c] = t;
    }
  }
  float biasv[4], gv[4], btv[4], b2v[4];
  float w1r[8][4], w2r[4][8];
  #pragma unroll
  for (int nt = 0; nt < 4; ++nt) {
    biasv[nt] = bias[nt*16 + lm];
    gv[nt]    = g[nt*16 + lm];
    btv[nt]   = bt[nt*16 + lm];
    b2v[nt]   = b2[nt*16 + lm];
    #pragma unroll
    for (int t = 0; t < 8; ++t) w2r[nt][t] = w2[(nt*16 + lm)*8 + t];
  }
  #pragma unroll
  for (int t = 0; t < 8; ++t)
    #pragma unroll
    for (int nt = 0; nt < 4; ++nt) w1r[t][nt] = w1[t*64 + nt*16 + lm];

  for (int rt = w0; rt < 19; rt += 4) {
    int rsrc = rt*16 + lm; if (rsrc > 300) rsrc = 300;
    const float* arow = ao + ((size_t)b*SEQ + rsrc)*64;
    f32x4 acc[4];
    #pragma unroll
    for (int nt = 0; nt < 4; ++nt)
      acc[nt] = (f32x4){biasv[nt], biasv[nt], biasv[nt], biasv[nt]};
    #pragma unroll
    for (int c = 0; c < 4; ++c) {
      float4 av = *(const float4*)(arow + c*16 + lq*4);
      s16x4 af;
      af.x = (short)f2bf(av.x); af.y = (short)f2bf(av.y);
      af.z = (short)f2bf(av.z); af.w = (short)f2bf(av.w);
      #pragma unroll
      for (int nt = 0; nt < 4; ++nt) acc[nt] = mm16(af, Bf[nt][c], acc[nt]);
    }
    int row0 = rt*16 + lq*4;
    float v[4][4];
    #pragma unroll
    for (int r = 0; r < 4; ++r) {
      int row = row0 + r; int rs2 = row > 300 ? 300 : row;
      const float* xr = x + ((size_t)b*SEQ + rs2)*64;
      #pragma unroll
      for (int nt = 0; nt < 4; ++nt) v[r][nt] = acc[nt][r] + xr[nt*16 + lm];
    }
    #pragma unroll
    for (int r = 0; r < 4; ++r) {
      float s = (v[r][0] + v[r][1]) + (v[r][2] + v[r][3]);
      s += __shfl_xor(s, 1, 64); s += __shfl_xor(s, 2, 64);
      s += __shfl_xor(s, 4, 64); s += __shfl_xor(s, 8, 64);
      float m = s * (1.f/64.f);
      float c0 = v[r][0]-m, c1 = v[r][1]-m, c2 = v[r][2]-m, c3 = v[r][3]-m;
      float s2 = (c0*c0 + c1*c1) + (c2*c2 + c3*c3);
      s2 += __shfl_xor(s2, 1, 64); s2 += __shfl_xor(s2, 2, 64);
      s2 += __shfl_xor(s2, 4, 64); s2 += __shfl_xor(s2, 8, 64);
      float rs = rsqrtf(s2*(1.f/64.f) + 1e-5f);
      float xn0 = c0*rs*gv[0] + btv[0];
      float xn1 = c1*rs*gv[1] + btv[1];
      float xn2 = c2*rs*gv[2] + btv[2];
      float xn3 = c3*rs*gv[3] + btv[3];
      float hg[8];
      #pragma unroll
      for (int t = 0; t < 8; ++t) {
        float p = xn0*w1r[t][0] + xn1*w1r[t][1] + xn2*w1r[t][2] + xn3*w1r[t][3];
        p += __shfl_xor(p, 1, 64); p += __shfl_xor(p, 2, 64);
        p += __shfl_xor(p, 4, 64); p += __shfl_xor(p, 8, 64);
        float a = p + b1[t];
        hg[t] = 0.5f*a*(1.f + erff(a*0.70710678f));
      }
      int row = row0 + r;
      if (row < SEQ) {
        float* xw = x + ((size_t)b*SEQ + row)*64;
        #pragma unroll
        for (int nt = 0; nt < 4; ++nt) {
          float o = 0.f;
          #pragma unroll
          for (int t = 0; t < 8; ++t) o += hg[t]*w2r[nt][t];
          xw[nt*16 + lm] = v[r][nt] + o + b2v[nt];
        }
      }
    }
  }
}

// ---------------- K10: head
__global__ __launch_bounds__(128) void k_head(const float* __restrict__ x,
    const float* __restrict__ y, const float* __restrict__ g, const float* __restrict__ bt,
    const float* __restrict__ hw, const float* __restrict__ hb, float* __restrict__ out) {
  int b = blockIdx.x; int t = threadIdx.x; int lane = t & 63; int wv = t >> 6;
  float v = (t < 64) ? x[(size_t)b*SEQ*64 + t] : y[(size_t)b*64 + t - 64];
  __shared__ float rbuf[2];
  __shared__ float z_s[128];
  float s = v;
  #pragma unroll
  for (int o = 32; o; o >>= 1) s += __shfl_down(s, o, 64);
  if (lane == 0) rbuf[wv] = s;
  __syncthreads();
  float m = (rbuf[0] + rbuf[1]) * (1.f/128.f);
  __syncthreads();
  float c = v - m;
  float s2 = c*c;
  #pragma unroll
  for (int o = 32; o; o >>= 1) s2 += __shfl_down(s2, o, 64);
  if (lane == 0) rbuf[wv] = s2;
  __syncthreads();
  float var = (rbuf[0] + rbuf[1]) * (1.f/128.f);
  z_s[t] = c * rsqrtf(var + 1e-5f) * g[t] + bt[t];
  __syncthreads();
  if (t < 16) {
    float a = hb[t];
    const float* wr = hw + t*128;
    #pragma unroll 8
    for (int j = 0; j < 128; ++j) a += z_s[j]*wr[j];
    out[(size_t)b*16 + t] = a;
  }
}

extern "C" void kernel_launch(void* const* d_in, const int* in_sizes, int n_in,
                              void* d_out, int out_size, void* d_ws, size_t ws_size,
                              hipStream_t stream) {
  const float* input      = (const float*)d_in[0];
  const float* sse_w      = (const float*)d_in[1];
  const float* sse_b      = (const float*)d_in[2];
  const float* conv1_w    = (const float*)d_in[3];
  const float* conv1_b    = (const float*)d_in[4];
  const float* conv2_w    = (const float*)d_in[5];
  const float* conv2_b    = (const float*)d_in[6];
  const float* dense1_w   = (const float*)d_in[7];
  const float* dense1_b   = (const float*)d_in[8];
  const float* patch_w    = (const float*)d_in[9];
  const float* patch_b    = (const float*)d_in[10];
  const float* cls_token  = (const float*)d_in[11];
  const float* pos_emb    = (const float*)d_in[12];
  const float* ln1_g      = (const float*)d_in[13];
  const float* ln1_b      = (const float*)d_in[14];
  const float* qkv_w      = (const float*)d_in[15];
  const float* attn_out_w = (const float*)d_in[16];
  const float* attn_out_b = (const float*)d_in[17];
  const float* ln2_g      = (const float*)d_in[18];
  const float* ln2_b      = (const float*)d_in[19];
  const float* ff1_w      = (const float*)d_in[20];
  const float* ff1_b      = (const float*)d_in[21];
  const float* ff2_w      = (const float*)d_in[22];
  const float* ff2_b      = (const float*)d_in[23];
  const float* head_ln_g  = (const float*)d_in[24];
  const float* head_ln_b  = (const float*)d_in[25];
  const float* head_w     = (const float*)d_in[26];
  const float* head_b     = (const float*)d_in[27];
  float* out = (float*)d_out;

  float* ws = (float*)d_ws;
  float* xs  = ws;                    // 3,840,000
  float* y   = xs + 3840000;          // 32,768
  float* x   = y + 32768;             // 9,863,168
  float* R   = x + 9863168;           // shared region
  // conv phase:
  float* c2  = R + 21676032;          // 4,784,128 floats (consumed by dense1 before qkv)
  // transformer phase (reuses R):
  float* ao  = R;
  unsigned short* q_g  = (unsigned short*)(R + 9863168);
  unsigned short* k_g  = q_g + 9961472;
  unsigned short* vt_g = k_g + 9961472;

  k_sse   <<<NB*25, 64, 0, stream>>>(input, sse_w, sse_b, xs);
  k_conv12<<<NB*4, 256, 0, stream>>>(xs, conv1_w, conv1_b, conv2_w, conv2_b, c2);
  k_dense1<<<NB, 256, 0, stream>>>(c2, dense1_w, dense1_b, y);
  k_patch <<<NB*SEQ/4, dim3(64,4), 0, stream>>>(xs, patch_w, patch_b, cls_token, pos_emb, x);
  for (int i = 0; i < 5; ++i) {
    k_qkv <<<NB, 256, 0, stream>>>(x, ln1_g + i*64, ln1_b + i*64,
                                   qkv_w + (size_t)i*192*64, q_g, k_g, vt_g);
    k_attn<<<NB*4, 256, 0, stream>>>(q_g, k_g, vt_g, ao);
    k_post<<<NB*4, 64, 0, stream>>>(ao,
                 attn_out_w + (size_t)i*4096, attn_out_b + i*64,
                 ln2_g + i*64, ln2_b + i*64,
                 ff1_w + (size_t)i*512, ff1_b + i*8, ff2_w + (size_t)i*512, ff2_b + i*64, x);
  }
  k_head<<<NB, 128, 0, stream>>>(x, y, head_ln_g, head_ln_b, head_w, head_b, out);
}